// Round 2
// baseline (15847.215 us; speedup 1.0000x reference)
//
#include <hip/hip_runtime.h>
#include <math.h>

// 4-layer LSTM (15/20/30/40), B=8192, T=512, fp32.
// 16 lanes per batch element (unit-parallel), 32 elements per 512-thread
// block, 256 blocks = 1 block/CU. Weights packed in LDS (read fused into the
// dot, no iv[] local arrays -> no scratch); h state per element in LDS with a
// baked-in 1.0 slot so bias rides the h-dot; c state + accumulators in regs.
// Strides chosen with S/4 odd so 16-row reads are 2-way bank aliased (free).

#define TSTEPS 512
#define NB     8192
#define INDIM  7
#define D1 15
#define D2 20
#define D3 30
#define D4 40

#define NE 32     // elements per block
#define NT 512    // threads per block

// per-element h layout in LDS (floats): blocks with constant-1.0 bias slot
// B1=16: [h1(15) 1.0] | B2=28: [h2(20) 1.0 0*7] | B3=32: [h3(30) 1.0 0]
// B4=44: [h4(40) 1.0 0*3]    HSTR = 120 (120%32=24 -> group windows disjoint)
#define HSTR 120
#define H1 0
#define H2 16
#define H3 44
#define H4 76

// weight row strides (floats), all with S/4 odd -> 2-way bank aliasing (free)
#define S1F 20    // [Whh1(15) bias 0*4]                    (Wih1 lives in regs)
#define S2F 44    // [Wih2(15) 0 | Whh2(20) bias 0*7]
#define S3F 60    // [Wih3(20) 0*8 | Whh3(30) bias 0]
#define S4F 76    // [Wih4(30) 0*2 | Whh4(40) bias 0*3]
// gate strides (floats)
#define GS1F (D1*S1F)   // 300
#define GS2F (D2*S2F)   // 880
#define GS3F (D3*S3F)   // 1800
#define GS4F (D4*S4F)   // 3040

#define W1SZ (4*D1*S1F)   // 1200
#define W2SZ (4*D2*S2F)   // 3520
#define W3SZ (4*D3*S3F)   // 7200
#define W4SZ (4*D4*S4F)   // 12160

__device__ __forceinline__ float sigm(float x)  { return 1.0f / (1.0f + expf(-x)); }
__device__ __forceinline__ float tanhp(float x) { return 1.0f - 2.0f / (expf(2.0f * x) + 1.0f); }

__device__ __forceinline__ float cell_up(const float (&a)[4], float& c) {
  float ii = sigm(a[0]);
  float ff = sigm(a[1]);
  float gg = tanhp(a[2]);
  float oo = sigm(a[3]);
  float cn = fmaf(ff, c, ii * gg);
  c = cn;
  return oo * tanhp(cn);
}

// fused dots: per float4 chunk, read iv once from LDS and FMA against the 4
// gate rows of 1/2/3 owned units. All offsets compile-time -> imm-offset
// ds_read_b128, no local arrays.
#define CHUNK_FMA(q, v, dst)                                                  \
  dst = fmaf((q).x, (v).x, fmaf((q).y, (v).y, fmaf((q).z, (v).z, fmaf((q).w, (v).w, dst))));

template<int NC, int GSF>
__device__ __forceinline__ void dot1(const float* w0, const float* iv, float (&a)[4]) {
#pragma unroll
  for (int c = 0; c < NC; ++c) {
    const float4 v = *(const float4*)(iv + 4 * c);
#pragma unroll
    for (int g = 0; g < 4; ++g) {
      const float4 q0 = *(const float4*)(w0 + g * GSF + 4 * c);
      CHUNK_FMA(q0, v, a[g]);
    }
  }
}

template<int NC, int GSF>
__device__ __forceinline__ void dot2(const float* w0, const float* w1,
                                     const float* iv, float (&a)[4], float (&b)[4]) {
#pragma unroll
  for (int c = 0; c < NC; ++c) {
    const float4 v = *(const float4*)(iv + 4 * c);
#pragma unroll
    for (int g = 0; g < 4; ++g) {
      const float4 q0 = *(const float4*)(w0 + g * GSF + 4 * c);
      CHUNK_FMA(q0, v, a[g]);
      const float4 q1 = *(const float4*)(w1 + g * GSF + 4 * c);
      CHUNK_FMA(q1, v, b[g]);
    }
  }
}

template<int NC, int GSF>
__device__ __forceinline__ void dot3(const float* w0, const float* w1, const float* w2,
                                     const float* iv,
                                     float (&a)[4], float (&b)[4], float (&cc)[4]) {
#pragma unroll
  for (int c = 0; c < NC; ++c) {
    const float4 v = *(const float4*)(iv + 4 * c);
#pragma unroll
    for (int g = 0; g < 4; ++g) {
      const float4 q0 = *(const float4*)(w0 + g * GSF + 4 * c);
      CHUNK_FMA(q0, v, a[g]);
      const float4 q1 = *(const float4*)(w1 + g * GSF + 4 * c);
      CHUNK_FMA(q1, v, b[g]);
      const float4 q2 = *(const float4*)(w2 + g * GSF + 4 * c);
      CHUNK_FMA(q2, v, cc[g]);
    }
  }
}

__device__ __forceinline__ void stage(float* dst, const float* Wih, const float* Whh,
                                      const float* bih, const float* bhh,
                                      int rows, int din, int hoff, int dh, int bcol,
                                      int stride, int tid) {
  for (int idx = tid; idx < rows * stride; idx += NT) {
    int r = idx / stride;
    int c = idx - r * stride;
    float v = 0.0f;
    if (c < din)                         v = Wih[r * din + c];
    else if (c >= hoff && c < hoff + dh) v = Whh[r * dh + (c - hoff)];
    else if (c == bcol)                  v = bih[r] + bhh[r];
    dst[idx] = v;
  }
}

__global__ void __launch_bounds__(NT, 2)
lstm_fused(const float* __restrict__ x,
           const float* __restrict__ Wih1, const float* __restrict__ Whh1,
           const float* __restrict__ bih1, const float* __restrict__ bhh1,
           const float* __restrict__ Wih2, const float* __restrict__ Whh2,
           const float* __restrict__ bih2, const float* __restrict__ bhh2,
           const float* __restrict__ Wih3, const float* __restrict__ Whh3,
           const float* __restrict__ bih3, const float* __restrict__ bhh3,
           const float* __restrict__ Wih4, const float* __restrict__ Whh4,
           const float* __restrict__ bih4, const float* __restrict__ bhh4,
           const float* __restrict__ Wl, const float* __restrict__ bl,
           float* __restrict__ out) {
  __shared__ __align__(16) float w1[W1SZ];
  __shared__ __align__(16) float w2[W2SZ];
  __shared__ __align__(16) float w3[W3SZ];
  __shared__ __align__(16) float w4[W4SZ];
  __shared__ __align__(16) float hs[NE][HSTR];
  __shared__ __align__(16) float obuf[NE][64];

  const int tid = threadIdx.x;

  // ---- one-time packed weight staging + h-state init (1.0 bias slots) ----
  stage(w1, (const float*)0, Whh1, bih1, bhh1, 4*D1, 0,  0,  D1, 15, S1F, tid);
  stage(w2, Wih2, Whh2, bih2, bhh2, 4*D2, D1, 16, D2, 36, S2F, tid);
  stage(w3, Wih3, Whh3, bih3, bhh3, 4*D3, D2, 28, D3, 58, S3F, tid);
  stage(w4, Wih4, Whh4, bih4, bhh4, 4*D4, D3, 32, D4, 72, S4F, tid);
  for (int i = tid; i < NE * HSTR; i += NT) {
    int c = i % HSTR;
    (&hs[0][0])[i] = (c == 15 || c == 36 || c == 74 || c == 116) ? 1.0f : 0.0f;
  }
  __syncthreads();  // only barrier in the kernel

  const int g   = tid >> 4;   // element group within block
  const int sub = tid & 15;   // lane within group
  const long b  = (long)blockIdx.x * NE + g;
  const float* __restrict__ xr = x + b * (TSTEPS * INDIM);
  float* hme  = hs[g];
  float* ob   = obuf[g];
  float* outp = out + b * TSTEPS;

  // clamped unit indices (inactive lanes compute a duplicate, never commit)
  const int u1  = (sub < D1)      ? sub        : (D1 - 1);
  const int u2b = (sub + 16 < D2) ? (sub + 16) : (D2 - 1);
  const int u3b = (sub + 16 < D3) ? (sub + 16) : (D3 - 1);
  const int u4c = (sub + 32 < D4) ? (sub + 32) : (D4 - 1);

  const float* w1p  = w1 + u1 * S1F;
  const float* w2pa = w2 + sub * S2F;
  const float* w2pb = w2 + u2b * S2F;
  const float* w3pa = w3 + sub * S3F;
  const float* w3pb = w3 + u3b * S3F;
  const float* w4pa = w4 + sub * S4F;
  const float* w4pb = w4 + (sub + 16) * S4F;
  const float* w4pc = w4 + u4c * S4F;

  // Wih1 (4 gates x 7) is loop-invariant and small: keep in registers
  float w1x[4][INDIM];
#pragma unroll
  for (int gg = 0; gg < 4; ++gg)
#pragma unroll
    for (int j = 0; j < INDIM; ++j)
      w1x[gg][j] = Wih1[(gg * D1 + u1) * INDIM + j];

  const float wla = Wl[sub];
  const float wlb = Wl[sub + 16];
  const float wlc = (sub + 32 < D4) ? Wl[sub + 32] : 0.0f;
  const float blv = bl[0];

  // cell state in registers (owned units per lane)
  float c1 = 0.f;
  float c2a = 0.f, c2b = 0.f;
  float c3a = 0.f, c3b = 0.f;
  float c4a = 0.f, c4b = 0.f, c4c = 0.f;

  // prefetch x for t=0
  float nx0 = xr[0], nx1 = xr[1], nx2 = xr[2], nx3 = xr[3],
        nx4 = xr[4], nx5 = xr[5], nx6 = xr[6];

#pragma unroll 1
  for (int t = 0; t < TSTEPS; ++t) {
    const float x0 = nx0, x1 = nx1, x2 = nx2, x3 = nx3, x4 = nx4, x5 = nx5, x6 = nx6;
    if (t + 1 < TSTEPS) {  // issue next-step x loads early; consumed next iter
      const float* nxr = xr + (t + 1) * INDIM;
      nx0 = nxr[0]; nx1 = nxr[1]; nx2 = nxr[2]; nx3 = nxr[3];
      nx4 = nxr[4]; nx5 = nxr[5]; nx6 = nxr[6];
    }

    // ---------- layer 1 ----------
    float A1[4] = {0.f, 0.f, 0.f, 0.f};
#pragma unroll
    for (int gg = 0; gg < 4; ++gg) {
      float s = w1x[gg][0] * x0;
      s = fmaf(w1x[gg][1], x1, s);
      s = fmaf(w1x[gg][2], x2, s);
      s = fmaf(w1x[gg][3], x3, s);
      s = fmaf(w1x[gg][4], x4, s);
      s = fmaf(w1x[gg][5], x5, s);
      s = fmaf(w1x[gg][6], x6, s);
      A1[gg] = s;
    }
    dot1<4, GS1F>(w1p, hme + H1, A1);          // Whh1 + bias vs [h1 | 1.0]
    float h1n = cell_up(A1, c1);
    if (sub < D1) hme[H1 + sub] = h1n;

    // ---------- layer 2 ----------
    float A2a[4] = {0.f,0.f,0.f,0.f}, A2b[4] = {0.f,0.f,0.f,0.f};
    dot2<4, GS2F>(w2pa,      w2pb,      hme + H1, A2a, A2b);  // Wih2 cols 0..15
    dot2<6, GS2F>(w2pa + 16, w2pb + 16, hme + H2, A2a, A2b);  // Whh2+bias cols 16..39
    float h2na = cell_up(A2a, c2a);
    float h2nb = cell_up(A2b, c2b);
    hme[H2 + sub] = h2na;
    if (sub + 16 < D2) hme[H2 + sub + 16] = h2nb;

    // ---------- layer 3 ----------
    float A3a[4] = {0.f,0.f,0.f,0.f}, A3b[4] = {0.f,0.f,0.f,0.f};
    dot2<6, GS3F>(w3pa,      w3pb,      hme + H2, A3a, A3b);  // Wih3 cols 0..23
    dot2<8, GS3F>(w3pa + 28, w3pb + 28, hme + H3, A3a, A3b);  // Whh3+bias cols 28..59
    float h3na = cell_up(A3a, c3a);
    float h3nb = cell_up(A3b, c3b);
    hme[H3 + sub] = h3na;
    if (sub + 16 < D3) hme[H3 + sub + 16] = h3nb;

    // ---------- layer 4 ----------
    float A4a[4] = {0.f,0.f,0.f,0.f}, A4b[4] = {0.f,0.f,0.f,0.f}, A4c[4] = {0.f,0.f,0.f,0.f};
    dot3<8,  GS4F>(w4pa,      w4pb,      w4pc,      hme + H3, A4a, A4b, A4c);  // Wih4
    dot3<11, GS4F>(w4pa + 32, w4pb + 32, w4pc + 32, hme + H4, A4a, A4b, A4c);  // Whh4+bias
    float h4na = cell_up(A4a, c4a);
    float h4nb = cell_up(A4b, c4b);
    float h4nc = cell_up(A4c, c4c);
    hme[H4 + sub] = h4na;
    hme[H4 + sub + 16] = h4nb;
    if (sub + 32 < D4) hme[H4 + sub + 32] = h4nc;

    // ---------- output: dot(h4, Wl) + bl ----------
    float part = fmaf(h4na, wla, fmaf(h4nb, wlb, h4nc * wlc));  // wlc=0 if inactive
    part += __shfl_xor(part, 8);
    part += __shfl_xor(part, 4);
    part += __shfl_xor(part, 2);
    part += __shfl_xor(part, 1);
    if (sub == 0) ob[t & 63] = part + blv;
    if ((t & 63) == 63) {  // coalesced flush of 64 timesteps
      float4 v = *(const float4*)(ob + (sub << 2));
      *(float4*)(outp + (t - 63) + (sub << 2)) = v;
    }
  }
}

extern "C" void kernel_launch(void* const* d_in, const int* in_sizes, int n_in,
                              void* d_out, int out_size, void* d_ws, size_t ws_size,
                              hipStream_t stream) {
  lstm_fused<<<dim3(NB / NE), dim3(NT), 0, stream>>>(
      (const float*)d_in[0],
      (const float*)d_in[1],  (const float*)d_in[2],  (const float*)d_in[3],  (const float*)d_in[4],
      (const float*)d_in[5],  (const float*)d_in[6],  (const float*)d_in[7],  (const float*)d_in[8],
      (const float*)d_in[9],  (const float*)d_in[10], (const float*)d_in[11], (const float*)d_in[12],
      (const float*)d_in[13], (const float*)d_in[14], (const float*)d_in[15], (const float*)d_in[16],
      (const float*)d_in[17], (const float*)d_in[18],
      (float*)d_out);
}

// Round 3
// 5848.746 us; speedup vs baseline: 2.7095x; 2.7095x over previous
//
#include <hip/hip_runtime.h>
#include <math.h>

// 4-layer LSTM (15/20/30/40), B=8192, T=512, fp32, no barriers in main loop.
// Layout: 256 blocks x 512 threads (1 block/CU, 8 waves). Each WAVE owns 4
// batch elements. Lane = (k in bits0-1 = K-quarter, s in bits2-5 = unit slot).
// Weights packed in LDS once; each weight ds_read_b128 is reused for 4
// elements (16 FMA/read) and each lane reads only its K-quarter -> LDS
// instrs/wave-step ~180 vs ~480 before. K-partial sums reduced across the
// lane quad with DPP quad_perm (VALU pipe), each k-lane keeping element e=k.

#define TSTEPS 512
#define NB     8192
#define D1 15
#define D2 20
#define D3 30
#define D4 40
#define NE 32
#define NT 512

// padded K per layer (multiple of 16 so each k-lane gets whole float4 chunks)
#define K1CH 2   // K1=32
#define K2CH 3   // K2=48
#define K3CH 4   // K3=64
#define K4CH 5   // K4=80
// weight row strides (floats); %32 in {4,20} spreads rows/gates across banks
#define R1 36
#define R2 52
#define R3 68
#define R4 84
// per-element iv/h layout in hs (floats)
#define SEC1 0    // [x(7)@0 pad h1(15)@8 1.0@23 pad..31]
#define SEC2 32   // [h1(15)@0 pad h2(20)@16 1.0@36 pad..47]
#define SEC3 80   // [h2(20)@0 h3(30)@20 1.0@50 pad..63]
#define SEC4 144  // [h3(30)@0 pad2 h4(40)@32 1.0@72 pad..79]
#define HSTR 228  // 228%32==4 -> element stride spreads banks

__device__ __forceinline__ float sigm(float x)  { return 1.0f/(1.0f+expf(-x)); }
__device__ __forceinline__ float tanhp(float x) { return 1.0f - 2.0f/(expf(2.0f*x)+1.0f); }

__device__ __forceinline__ float cell4(const float (&g)[4], float& c){
  float ii = sigm(g[0]);
  float ff = sigm(g[1]);
  float gg = tanhp(g[2]);
  float oo = sigm(g[3]);
  c = fmaf(ff, c, ii*gg);
  return oo*tanhp(c);
}

template<int CTRL>
__device__ __forceinline__ float dppmv(float x){
  return __int_as_float(__builtin_amdgcn_mov_dpp(__float_as_int(x), CTRL, 0xF, 0xF, false));
}

// a[e] = this lane's K-quarter partial for element e. Returns the full
// 4-quarter sum for element e == (lane&3). quad_perm xor1=0xB1, xor2=0x4E.
__device__ __forceinline__ float quad_reduce_sel(const float (&a)[4], bool b0, bool b1){
  float c0 = a[0] + dppmv<0xB1>(a[0]);   // c[e] = pair sum over bit0
  float c1 = a[1] + dppmv<0xB1>(a[1]);
  float c2 = a[2] + dppmv<0xB1>(a[2]);
  float c3 = a[3] + dppmv<0xB1>(a[3]);
  float m = b0 ? c1 : c0;                // c[bit0]   (agrees across xor2 pair)
  float n = b0 ? c3 : c2;                // c[2+bit0]
  m += dppmv<0x4E>(m);                   // S[bit0]
  n += dppmv<0x4E>(n);                   // S[2+bit0]
  return b1 ? n : m;                     // S[k]
}

// one layer: dot over this lane's K-quarter for NU unit-slots x 4 gates x 4
// elements, then quad-reduce to S[u][g] for element e = lane&3.
template<int NU, int NCH, int RSTR, int SEC>
__device__ __forceinline__ void layer_pass(const float* const (&wb)[NU],
    const float* const (&ivp)[4], bool b0, bool b1, float (&S)[NU][4]){
  float acc[NU][4][4] = {};
#pragma unroll
  for (int j = 0; j < NCH; ++j){
    const float4 v0 = *(const float4*)(ivp[0] + SEC + 16*j);
    const float4 v1 = *(const float4*)(ivp[1] + SEC + 16*j);
    const float4 v2 = *(const float4*)(ivp[2] + SEC + 16*j);
    const float4 v3 = *(const float4*)(ivp[3] + SEC + 16*j);
#pragma unroll
    for (int u = 0; u < NU; ++u){
#pragma unroll
      for (int g = 0; g < 4; ++g){
        const float4 wq = *(const float4*)(wb[u] + g*RSTR + 16*j);
        float* a = acc[u][g];
        a[0]=fmaf(wq.x,v0.x,a[0]); a[0]=fmaf(wq.y,v0.y,a[0]); a[0]=fmaf(wq.z,v0.z,a[0]); a[0]=fmaf(wq.w,v0.w,a[0]);
        a[1]=fmaf(wq.x,v1.x,a[1]); a[1]=fmaf(wq.y,v1.y,a[1]); a[1]=fmaf(wq.z,v1.z,a[1]); a[1]=fmaf(wq.w,v1.w,a[1]);
        a[2]=fmaf(wq.x,v2.x,a[2]); a[2]=fmaf(wq.y,v2.y,a[2]); a[2]=fmaf(wq.z,v2.z,a[2]); a[2]=fmaf(wq.w,v2.w,a[2]);
        a[3]=fmaf(wq.x,v3.x,a[3]); a[3]=fmaf(wq.y,v3.y,a[3]); a[3]=fmaf(wq.z,v3.z,a[3]); a[3]=fmaf(wq.w,v3.w,a[3]);
      }
    }
  }
#pragma unroll
  for (int u = 0; u < NU; ++u)
#pragma unroll
    for (int g = 0; g < 4; ++g)
      S[u][g] = quad_reduce_sel(acc[u][g], b0, b1);
}

// pack [Wih | pad | Whh | bias(=bih+bhh) | zeros] rows, row index = u*4+g
__device__ void stageW(float* dst, const float* Wih, const float* Whh,
                       const float* bih, const float* bhh,
                       int dh, int din, int hoff, int bcol, int R, int tid){
  const int total = 4*dh*R;
  for (int idx = tid; idx < total; idx += NT){
    int lrow = idx / R;
    int c = idx - lrow*R;
    int u = lrow >> 2, g = lrow & 3;
    int srow = g*dh + u;
    float v = 0.0f;
    if (c < din)                         v = Wih[srow*din + c];
    else if (c >= hoff && c < hoff+dh)   v = Whh[srow*dh + (c-hoff)];
    else if (c == bcol)                  v = bih[srow] + bhh[srow];
    dst[idx] = v;
  }
}

__global__ void __launch_bounds__(NT, 2)
lstm_fused(const float* __restrict__ x,
           const float* __restrict__ Wih1, const float* __restrict__ Whh1,
           const float* __restrict__ bih1, const float* __restrict__ bhh1,
           const float* __restrict__ Wih2, const float* __restrict__ Whh2,
           const float* __restrict__ bih2, const float* __restrict__ bhh2,
           const float* __restrict__ Wih3, const float* __restrict__ Whh3,
           const float* __restrict__ bih3, const float* __restrict__ bhh3,
           const float* __restrict__ Wih4, const float* __restrict__ Whh4,
           const float* __restrict__ bih4, const float* __restrict__ bhh4,
           const float* __restrict__ Wl, const float* __restrict__ bl,
           float* __restrict__ out) {
  __shared__ __align__(16) float w1[4*D1*R1];   // 2160 f
  __shared__ __align__(16) float w2[4*D2*R2];   // 4160 f
  __shared__ __align__(16) float w3[4*D3*R3];   // 8160 f
  __shared__ __align__(16) float w4[4*D4*R4];   // 13440 f
  __shared__ __align__(16) float hs[NE*HSTR];   // 7296 f
  __shared__ __align__(16) float obuf[NE*64];   // 2048 f  -> total 149 KB

  const int tid = threadIdx.x;

  stageW(w1, Wih1, Whh1, bih1, bhh1, D1, 7,  8,  23, R1, tid);
  stageW(w2, Wih2, Whh2, bih2, bhh2, D2, 15, 16, 36, R2, tid);
  stageW(w3, Wih3, Whh3, bih3, bhh3, D3, 20, 20, 50, R3, tid);
  stageW(w4, Wih4, Whh4, bih4, bhh4, D4, 30, 32, 72, R4, tid);
  for (int i = tid; i < NE*HSTR; i += NT){
    int c = i % HSTR;
    hs[i] = (c == SEC1+23 || c == SEC2+36 || c == SEC3+50 || c == SEC4+72) ? 1.0f : 0.0f;
  }
  __syncthreads();   // only barrier in the kernel

  const int wv   = tid >> 6;          // wave id: owns elements 4*wv..4*wv+3
  const int lane = tid & 63;
  const int k    = lane & 3;          // K-quarter
  const int s    = lane >> 2;         // unit slot 0..15
  const bool b0  = (k & 1) != 0;
  const bool b1  = (k & 2) != 0;
  const int ek   = (wv << 2) | k;     // this lane's epilogue element (local)
  const long gb  = (long)blockIdx.x * NE;

  // unit assignments per slot (clamped slots compute duplicates, never commit)
  const int u1  = (s < 15) ? s      : 14;
  const int u2b = (s < 4)  ? 16 + s : 19;
  const int u3b = (s < 14) ? 16 + s : 29;
  const int u4c = (s < 8)  ? 32 + s : 39;

  const float* wb1[1] = { w1 + (u1*4)*R1 + 4*k };
  const float* wb2[2] = { w2 + (s*4)*R2 + 4*k,  w2 + (u2b*4)*R2 + 4*k };
  const float* wb3[2] = { w3 + (s*4)*R3 + 4*k,  w3 + (u3b*4)*R3 + 4*k };
  const float* wb4[3] = { w4 + (s*4)*R4 + 4*k,  w4 + ((16+s)*4)*R4 + 4*k,
                          w4 + (u4c*4)*R4 + 4*k };

  const float* ivp[4] = { hs + ((wv<<2)|0)*HSTR + 4*k,
                          hs + ((wv<<2)|1)*HSTR + 4*k,
                          hs + ((wv<<2)|2)*HSTR + 4*k,
                          hs + ((wv<<2)|3)*HSTR + 4*k };

  float* hb = hs + ek*HSTR;           // epilogue writes for element ek
  float* ob = obuf + ek*64;

  const float* xp = x + (gb + ek)*(TSTEPS*7) + (s < 7 ? s : 6);
  float xcur = xp[0];

  const float wlA = Wl[s];
  const float wlB = Wl[16+s];
  const float wlC = (s < 8) ? Wl[32+s] : 0.0f;
  const float blv = bl[0];

  float c1=0.f, c2a=0.f, c2b=0.f, c3a=0.f, c3b=0.f, c4a=0.f, c4b=0.f, c4c=0.f;

  // output flush mapping (wave-internal): 4 rows x 64 floats per wave
  const int fel = (wv << 2) | (lane >> 4);
  const int fj  = (lane & 15) << 2;
  const float* fob = obuf + fel*64 + fj;
  float* fout = out + (gb + fel)*TSTEPS + fj;

#pragma unroll 1
  for (int t = 0; t < TSTEPS; ++t){
    if (s < 7) hb[SEC1 + s] = xcur;                 // stage x_t for element ek
    xcur = (t + 1 < TSTEPS) ? xp[7] : 0.0f;         // prefetch x_{t+1}
    xp += 7;

    // ---- layer 1 ----
    float S1[1][4];
    layer_pass<1, K1CH, R1, SEC1>(wb1, ivp, b0, b1, S1);
    float h1 = cell4(S1[0], c1);
    if (s < 15) { hb[SEC1+8+s] = h1;  hb[SEC2+s]    = h1; }

    // ---- layer 2 ----
    float S2[2][4];
    layer_pass<2, K2CH, R2, SEC2>(wb2, ivp, b0, b1, S2);
    float h2a = cell4(S2[0], c2a);
    float h2b = cell4(S2[1], c2b);
    hb[SEC2+16+s] = h2a;  hb[SEC3+s] = h2a;
    if (s < 4) { hb[SEC2+32+s] = h2b;  hb[SEC3+16+s] = h2b; }

    // ---- layer 3 ----
    float S3[2][4];
    layer_pass<2, K3CH, R3, SEC3>(wb3, ivp, b0, b1, S3);
    float h3a = cell4(S3[0], c3a);
    float h3b = cell4(S3[1], c3b);
    hb[SEC3+20+s] = h3a;  hb[SEC4+s] = h3a;
    if (s < 14) { hb[SEC3+36+s] = h3b;  hb[SEC4+16+s] = h3b; }

    // ---- layer 4 ----
    float S4[3][4];
    layer_pass<3, K4CH, R4, SEC4>(wb4, ivp, b0, b1, S4);
    float h4a = cell4(S4[0], c4a);
    float h4b = cell4(S4[1], c4b);
    float h4c = cell4(S4[2], c4c);
    hb[SEC4+32+s] = h4a;
    hb[SEC4+48+s] = h4b;
    if (s < 8) hb[SEC4+64+s] = h4c;

    // ---- output: dot(h4, Wl) + bl, reduced over the 16 unit slots ----
    float part = fmaf(h4a, wlA, fmaf(h4b, wlB, h4c*wlC));
    part += __shfl_xor(part, 4);
    part += __shfl_xor(part, 8);
    part += __shfl_xor(part, 16);
    part += __shfl_xor(part, 32);
    if (s == 0) ob[t & 63] = part + blv;

    if ((t & 63) == 63) {                            // wave-internal flush
      float4 v = *(const float4*)fob;
      *(float4*)(fout + (t - 63)) = v;
    }
  }
}

extern "C" void kernel_launch(void* const* d_in, const int* in_sizes, int n_in,
                              void* d_out, int out_size, void* d_ws, size_t ws_size,
                              hipStream_t stream) {
  lstm_fused<<<dim3(NB / NE), dim3(NT), 0, stream>>>(
      (const float*)d_in[0],
      (const float*)d_in[1],  (const float*)d_in[2],  (const float*)d_in[3],  (const float*)d_in[4],
      (const float*)d_in[5],  (const float*)d_in[6],  (const float*)d_in[7],  (const float*)d_in[8],
      (const float*)d_in[9],  (const float*)d_in[10], (const float*)d_in[11], (const float*)d_in[12],
      (const float*)d_in[13], (const float*)d_in[14], (const float*)d_in[15], (const float*)d_in[16],
      (const float*)d_in[17], (const float*)d_in[18],
      (float*)d_out);
}

// Round 4
// 3885.487 us; speedup vs baseline: 4.0786x; 1.5053x over previous
//
#include <hip/hip_runtime.h>
#include <math.h>

// 4-layer LSTM (15/20/30/40), B=8192, T=512, fp32 in/out, MFMA version.
// 256 blocks x 512 threads; block owns 32 elements (= MFMA N dim).
// Weights: split-bf16 (hi+lo) A-fragments resident in REGISTERS (one-time
// global gather). Per step, per layer: D = A_hi*B_hi + A_hi*B_lo + A_lo*B_hi
// with v_mfma_f32_32x32x16_bf16 (error ~2^-17, fp32 accum). Weight rows
// reordered to 4u+g so each lane's 16 C regs = 4 units x 4 gates for one
// element => activations + c-state fully lane-local.
// iv vectors (bf16 hi/lo) in LDS: [prev-layer h | 1.0(bias) | own h], own-h
// part double-buffered by step parity => no same-phase read/write races.
// 4 barriers per step. Tiles statically assigned to waves (<=1 per phase).

#define NT 512
#define TS 512
#define D1 15
#define D2 20
#define D3 30
#define D4 40

typedef __attribute__((ext_vector_type(8))) short short8v;
typedef __attribute__((ext_vector_type(16))) float f32x16;

// iv element strides (ushort units) and slice offsets in S
#define E1 40   // K=23 (x7,1,h1@8..22), frags read k<32
#define E2 56   // K=36 (h1@0..14,1@15,h2@16..35), read k<48
#define E3 72   // K=51 (h2,1@20,h3@21..50), read k<64
#define E4 88   // K=71 (h3,1@30,h4@31..70), read k<80
#define IV1H 0
#define IV1L (IV1H + 2*32*E1)
#define IV2H (IV1H + 4*32*E1)
#define IV2L (IV2H + 2*32*E2)
#define IV3H (IV2H + 4*32*E2)
#define IV3L (IV3H + 2*32*E3)
#define IV4H (IV3H + 4*32*E3)
#define IV4L (IV4H + 2*32*E4)
#define STOT (IV4H + 4*32*E4)   // 32768 ushorts = 64KB
#define SCR_STR 44
#define OB_STR 68

__device__ __forceinline__ float sigm(float x)  { return 1.0f/(1.0f+expf(-x)); }
__device__ __forceinline__ float tanhp(float x) { return 1.0f - 2.0f/(expf(2.0f*x)+1.0f); }

// f32 -> bf16 bits, round-to-nearest-even
__device__ __forceinline__ unsigned short bfr(float f){
  unsigned u = __float_as_uint(f);
  u += 0x7FFFu + ((u >> 16) & 1u);
  return (unsigned short)(u >> 16);
}
__device__ __forceinline__ float bfv(unsigned short s){
  return __uint_as_float(((unsigned)s) << 16);
}

// Gather one 32-row M-tile of split-bf16 A-fragments from global fp32 weights.
// Packed row = 4u+g (PyTorch gate order i,f,g,o = source row g*DL+u).
// Column map (matches iv): k<DIN: Wih[.][k]; k==DIN: bih+bhh; DIN<k<DIN+1+DL:
// Whh[.][k-DIN-1]; else 0.  A-frag: lane holds row=lane&31, k=kt*16+8*(l>>5)+j.
template<int KT, int OFF>
__device__ void gatherA(short8v (&ah)[9], short8v (&al)[9], int lane, int m,
                        const float* Wih, const float* Whh,
                        const float* bih, const float* bhh, int DL, int DIN) {
  const int up = lane >> 5, rl = lane & 31;
  const int grow = m*32 + rl;
  const int u = grow >> 2, g = grow & 3;
#pragma unroll
  for (int kt = 0; kt < KT; ++kt) {
#pragma unroll
    for (int j = 0; j < 8; ++j) {
      const int k = kt*16 + up*8 + j;
      float v = 0.0f;
      if (u < DL) {
        const int srow = g*DL + u;
        if (k < DIN)                 v = Wih[srow*DIN + k];
        else if (k == DIN)           v = bih[srow] + bhh[srow];
        else if (k < DIN + 1 + DL)   v = Whh[srow*DL + (k - DIN - 1)];
      }
      const unsigned short hi = bfr(v);
      const unsigned short lo = bfr(v - bfv(hi));
      ah[OFF+kt][j] = (short)hi;
      al[OFF+kt][j] = (short)lo;
    }
  }
}

// One 32-row tile: 3-term split-bf16 MFMA + lane-local cell update + h writes.
template<int KT, int OFF>
__device__ __forceinline__ void doTile(const short8v (&ah)[9], const short8v (&al)[9],
    const unsigned short* ivH, const unsigned short* ivL, const int estr,
    float (&cst)[4], const int u0, const int DL,
    unsigned short* recH, unsigned short* recL, const int rec_estr, const int rec_k0,
    unsigned short* nxtH, unsigned short* nxtL, const int nxt_estr, const int nxt_k0,
    float* scr, const int n, const int up) {
  const unsigned short* bh = ivH + n*estr + up*8;
  const unsigned short* bl = ivL + n*estr + up*8;
  short8v Bh[KT], Bl[KT];
#pragma unroll
  for (int kt = 0; kt < KT; ++kt) Bh[kt] = *(const short8v*)(bh + 16*kt);
#pragma unroll
  for (int kt = 0; kt < KT; ++kt) Bl[kt] = *(const short8v*)(bl + 16*kt);
  f32x16 a1 = {}; f32x16 a2 = {};
#pragma unroll
  for (int kt = 0; kt < KT; ++kt)
    a1 = __builtin_amdgcn_mfma_f32_32x32x16_bf16(ah[OFF+kt], Bh[kt], a1, 0, 0, 0);
#pragma unroll
  for (int kt = 0; kt < KT; ++kt)
    a2 = __builtin_amdgcn_mfma_f32_32x32x16_bf16(ah[OFF+kt], Bl[kt], a2, 0, 0, 0);
#pragma unroll
  for (int kt = 0; kt < KT; ++kt)
    a2 = __builtin_amdgcn_mfma_f32_32x32x16_bf16(al[OFF+kt], Bh[kt], a2, 0, 0, 0);
  // C layout (m74/m101): col = lane&31 = element, row = (q&3)+8*(q>>2)+4*up
  // => reg q=4r+g holds gate g of unit u = u0+2r+up for element n.
#pragma unroll
  for (int r = 0; r < 4; ++r) {
    const float gi = a1[4*r+0] + a2[4*r+0];
    const float gf = a1[4*r+1] + a2[4*r+1];
    const float gg = a1[4*r+2] + a2[4*r+2];
    const float go = a1[4*r+3] + a2[4*r+3];
    const float ii = sigm(gi), ff = sigm(gf), g2 = tanhp(gg), oo = sigm(go);
    cst[r] = fmaf(ff, cst[r], ii * g2);
    const float h = oo * tanhp(cst[r]);
    const int u = u0 + 2*r + up;
    if (u < DL) {
      const unsigned short hi = bfr(h);
      const unsigned short lo = bfr(h - bfv(hi));
      recH[n*rec_estr + rec_k0 + u] = hi;
      recL[n*rec_estr + rec_k0 + u] = lo;
      if (nxtH) { nxtH[n*nxt_estr + nxt_k0 + u] = hi;
                  nxtL[n*nxt_estr + nxt_k0 + u] = lo; }
      if (scr)  scr[n*SCR_STR + u] = h;
    }
  }
}

__global__ void __launch_bounds__(NT, 2)
lstm_mfma(const float* __restrict__ x,
          const float* __restrict__ Wih1, const float* __restrict__ Whh1,
          const float* __restrict__ bih1, const float* __restrict__ bhh1,
          const float* __restrict__ Wih2, const float* __restrict__ Whh2,
          const float* __restrict__ bih2, const float* __restrict__ bhh2,
          const float* __restrict__ Wih3, const float* __restrict__ Whh3,
          const float* __restrict__ bih3, const float* __restrict__ bhh3,
          const float* __restrict__ Wih4, const float* __restrict__ Whh4,
          const float* __restrict__ bih4, const float* __restrict__ bhh4,
          const float* __restrict__ Wl, const float* __restrict__ bl,
          float* __restrict__ out) {
  __shared__ __align__(16) unsigned short S[STOT];
  __shared__ __align__(16) float scr[32*SCR_STR];
  __shared__ __align__(16) float obuf[32*OB_STR];

  const int tid = threadIdx.x;
  const int wv = tid >> 6, lane = tid & 63;
  const int n = lane & 31, up = lane >> 5;
  const long gb = (long)blockIdx.x * 32;

  // ---- zero LDS ----
  for (int i = tid; i < STOT/2; i += NT) ((unsigned*)S)[i] = 0u;
  for (int i = tid; i < 32*SCR_STR; i += NT) scr[i] = 0.0f;
  __syncthreads();
  // 1.0 bias slots (both parity buffers)
  if (tid < 64) {
    const int nn = tid & 31, b = tid >> 5;
    S[IV1H + b*32*E1 + nn*E1 + 7]  = 0x3F80;
    S[IV2H + b*32*E2 + nn*E2 + 15] = 0x3F80;
    S[IV3H + b*32*E3 + nn*E3 + 20] = 0x3F80;
    S[IV4H + b*32*E4 + nn*E4 + 30] = 0x3F80;
  }

  // ---- one-time A-fragment gather (registers, per wave role) ----
  // w0: A0(L1 m0) + C0(L3 m0); w1: A1 + C1; w2: y + B0(L2 m0) + C2;
  // w3: B1 + D4(L4 m4); w4: B2 + D0; w5: x + C3(L3 m3) + D1; w6: D2; w7: D3
  short8v ah[9], al[9];
  if      (wv == 0) { gatherA<2,0>(ah,al,lane,0,Wih1,Whh1,bih1,bhh1,D1,7);
                      gatherA<4,2>(ah,al,lane,0,Wih3,Whh3,bih3,bhh3,D3,20); }
  else if (wv == 1) { gatherA<2,0>(ah,al,lane,1,Wih1,Whh1,bih1,bhh1,D1,7);
                      gatherA<4,2>(ah,al,lane,1,Wih3,Whh3,bih3,bhh3,D3,20); }
  else if (wv == 2) { gatherA<3,0>(ah,al,lane,0,Wih2,Whh2,bih2,bhh2,D2,15);
                      gatherA<4,3>(ah,al,lane,2,Wih3,Whh3,bih3,bhh3,D3,20); }
  else if (wv == 3) { gatherA<3,0>(ah,al,lane,1,Wih2,Whh2,bih2,bhh2,D2,15);
                      gatherA<5,3>(ah,al,lane,4,Wih4,Whh4,bih4,bhh4,D4,30); }
  else if (wv == 4) { gatherA<3,0>(ah,al,lane,2,Wih2,Whh2,bih2,bhh2,D2,15);
                      gatherA<5,3>(ah,al,lane,0,Wih4,Whh4,bih4,bhh4,D4,30); }
  else if (wv == 5) { gatherA<4,0>(ah,al,lane,3,Wih3,Whh3,bih3,bhh3,D3,20);
                      gatherA<5,4>(ah,al,lane,1,Wih4,Whh4,bih4,bhh4,D4,30); }
  else if (wv == 6) { gatherA<5,0>(ah,al,lane,2,Wih4,Whh4,bih4,bhh4,D4,30); }
  else              { gatherA<5,0>(ah,al,lane,3,Wih4,Whh4,bih4,bhh4,D4,30); }

  // output weights (used by w2 only)
  float wlv[20];
#pragma unroll
  for (int j = 0; j < 20; ++j) wlv[j] = Wl[up*20 + j];
  const float blv = bl[0];

  float c0s[4] = {0,0,0,0}, c1s[4] = {0,0,0,0};

  // x(0) preload -> iv1 buf0
  if (wv == 5) {
    const float* xa = x + (gb + n)*(TS*7);
    unsigned short* dH = S + IV1H + n*E1;
    unsigned short* dL = S + IV1L + n*E1;
    if (up == 0) {
#pragma unroll
      for (int i = 0; i < 4; ++i) { float v = xa[i]; unsigned short h = bfr(v);
        dH[i] = h; dL[i] = bfr(v - bfv(h)); }
    } else {
#pragma unroll
      for (int i = 4; i < 7; ++i) { float v = xa[i]; unsigned short h = bfr(v);
        dH[i] = h; dL[i] = bfr(v - bfv(h)); }
    }
  }
  __syncthreads();

#pragma unroll 1
  for (int t = 0; t < TS; ++t) {
    const int cb = t & 1, nb = cb ^ 1;
    unsigned short* i1H = S + IV1H + cb*32*E1; unsigned short* i1L = S + IV1L + cb*32*E1;
    unsigned short* i1Hn= S + IV1H + nb*32*E1; unsigned short* i1Ln= S + IV1L + nb*32*E1;
    unsigned short* i2H = S + IV2H + cb*32*E2; unsigned short* i2L = S + IV2L + cb*32*E2;
    unsigned short* i2Hn= S + IV2H + nb*32*E2; unsigned short* i2Ln= S + IV2L + nb*32*E2;
    unsigned short* i3H = S + IV3H + cb*32*E3; unsigned short* i3L = S + IV3L + cb*32*E3;
    unsigned short* i3Hn= S + IV3H + nb*32*E3; unsigned short* i3Ln= S + IV3L + nb*32*E3;
    unsigned short* i4H = S + IV4H + cb*32*E4; unsigned short* i4L = S + IV4L + cb*32*E4;
    unsigned short* i4Hn= S + IV4H + nb*32*E4; unsigned short* i4Ln= S + IV4L + nb*32*E4;

    // ---------------- phase 1: L1 (w0,w1) | y(t-1) (w2) | x(t+1) (w5) ------
    if      (wv == 0) doTile<2,0>(ah,al, i1H,i1L,E1, c0s, 0, D1,
                                  i1Hn,i1Ln,E1,8, i2H,i2L,E2,0, nullptr, n, up);
    else if (wv == 1) doTile<2,0>(ah,al, i1H,i1L,E1, c0s, 8, D1,
                                  i1Hn,i1Ln,E1,8, i2H,i2L,E2,0, nullptr, n, up);
    else if (wv == 2) {
      if (t > 0) {
        const float* sp = scr + n*SCR_STR + up*20;
        float part = 0.0f;
#pragma unroll
        for (int q = 0; q < 5; ++q) {
          const float4 v = *(const float4*)(sp + 4*q);
          part = fmaf(v.x, wlv[4*q+0], part);
          part = fmaf(v.y, wlv[4*q+1], part);
          part = fmaf(v.z, wlv[4*q+2], part);
          part = fmaf(v.w, wlv[4*q+3], part);
        }
        part += __shfl_xor(part, 32);
        if (lane < 32) obuf[n*OB_STR + ((t-1) & 63)] = part + blv;
        if ((t & 63) == 0) {   // t>=64 here; flush y(t-64..t-1)
          __asm__ volatile("s_waitcnt lgkmcnt(0)" ::: "memory");
#pragma unroll
          for (int it = 0; it < 8; ++it) {
            const int row = it*4 + (lane >> 4), col = (lane & 15) << 2;
            const float4 v = *(const float4*)(obuf + row*OB_STR + col);
            *(float4*)(out + (gb + row)*TS + (t - 64) + col) = v;
          }
        }
      }
    }
    else if (wv == 5) {
      if (t + 1 < TS) {
        const float* xa = x + (gb + n)*(TS*7) + (t+1)*7;
        unsigned short* dH = i1Hn + n*E1;
        unsigned short* dL = i1Ln + n*E1;
        if (up == 0) {
#pragma unroll
          for (int i = 0; i < 4; ++i) { float v = xa[i]; unsigned short h = bfr(v);
            dH[i] = h; dL[i] = bfr(v - bfv(h)); }
        } else {
#pragma unroll
          for (int i = 4; i < 7; ++i) { float v = xa[i]; unsigned short h = bfr(v);
            dH[i] = h; dL[i] = bfr(v - bfv(h)); }
        }
      }
    }
    __syncthreads();

    // ---------------- phase 2: L2 (w2,w3,w4) --------------------------------
    if      (wv == 2) doTile<3,0>(ah,al, i2H,i2L,E2, c0s, 0,  D2,
                                  i2Hn,i2Ln,E2,16, i3H,i3L,E3,0, nullptr, n, up);
    else if (wv == 3) doTile<3,0>(ah,al, i2H,i2L,E2, c0s, 8,  D2,
                                  i2Hn,i2Ln,E2,16, i3H,i3L,E3,0, nullptr, n, up);
    else if (wv == 4) doTile<3,0>(ah,al, i2H,i2L,E2, c0s, 16, D2,
                                  i2Hn,i2Ln,E2,16, i3H,i3L,E3,0, nullptr, n, up);
    __syncthreads();

    // ---------------- phase 3: L3 (w0,w1,w2,w5) -----------------------------
    if      (wv == 0) doTile<4,2>(ah,al, i3H,i3L,E3, c1s, 0,  D3,
                                  i3Hn,i3Ln,E3,21, i4H,i4L,E4,0, nullptr, n, up);
    else if (wv == 1) doTile<4,2>(ah,al, i3H,i3L,E3, c1s, 8,  D3,
                                  i3Hn,i3Ln,E3,21, i4H,i4L,E4,0, nullptr, n, up);
    else if (wv == 2) doTile<4,3>(ah,al, i3H,i3L,E3, c1s, 16, D3,
                                  i3Hn,i3Ln,E3,21, i4H,i4L,E4,0, nullptr, n, up);
    else if (wv == 5) doTile<4,0>(ah,al, i3H,i3L,E3, c0s, 24, D3,
                                  i3Hn,i3Ln,E3,21, i4H,i4L,E4,0, nullptr, n, up);
    __syncthreads();

    // ---------------- phase 4: L4 (w3,w4,w5,w6,w7) --------------------------
    if      (wv == 3) doTile<5,3>(ah,al, i4H,i4L,E4, c1s, 32, D4,
                                  i4Hn,i4Ln,E4,31, nullptr,nullptr,0,0, scr, n, up);
    else if (wv == 4) doTile<5,3>(ah,al, i4H,i4L,E4, c1s, 0,  D4,
                                  i4Hn,i4Ln,E4,31, nullptr,nullptr,0,0, scr, n, up);
    else if (wv == 5) doTile<5,4>(ah,al, i4H,i4L,E4, c1s, 8,  D4,
                                  i4Hn,i4Ln,E4,31, nullptr,nullptr,0,0, scr, n, up);
    else if (wv == 6) doTile<5,0>(ah,al, i4H,i4L,E4, c0s, 16, D4,
                                  i4Hn,i4Ln,E4,31, nullptr,nullptr,0,0, scr, n, up);
    else if (wv == 7) doTile<5,0>(ah,al, i4H,i4L,E4, c0s, 24, D4,
                                  i4Hn,i4Ln,E4,31, nullptr,nullptr,0,0, scr, n, up);
    __syncthreads();
  }

  // ---- tail: y(511) + final flush (w2 only; scr from phase4 t=511) ----
  if (wv == 2) {
    const float* sp = scr + n*SCR_STR + up*20;
    float part = 0.0f;
#pragma unroll
    for (int q = 0; q < 5; ++q) {
      const float4 v = *(const float4*)(sp + 4*q);
      part = fmaf(v.x, wlv[4*q+0], part);
      part = fmaf(v.y, wlv[4*q+1], part);
      part = fmaf(v.z, wlv[4*q+2], part);
      part = fmaf(v.w, wlv[4*q+3], part);
    }
    part += __shfl_xor(part, 32);
    if (lane < 32) obuf[n*OB_STR + 63] = part + blv;
    __asm__ volatile("s_waitcnt lgkmcnt(0)" ::: "memory");
#pragma unroll
    for (int it = 0; it < 8; ++it) {
      const int row = it*4 + (lane >> 4), col = (lane & 15) << 2;
      const float4 v = *(const float4*)(obuf + row*OB_STR + col);
      *(float4*)(out + (gb + row)*TS + 448 + col) = v;
    }
  }
}

extern "C" void kernel_launch(void* const* d_in, const int* in_sizes, int n_in,
                              void* d_out, int out_size, void* d_ws, size_t ws_size,
                              hipStream_t stream) {
  lstm_mfma<<<dim3(8192/32), dim3(NT), 0, stream>>>(
      (const float*)d_in[0],
      (const float*)d_in[1],  (const float*)d_in[2],  (const float*)d_in[3],  (const float*)d_in[4],
      (const float*)d_in[5],  (const float*)d_in[6],  (const float*)d_in[7],  (const float*)d_in[8],
      (const float*)d_in[9],  (const float*)d_in[10], (const float*)d_in[11], (const float*)d_in[12],
      (const float*)d_in[13], (const float*)d_in[14], (const float*)d_in[15], (const float*)d_in[16],
      (const float*)d_in[17], (const float*)d_in[18],
      (float*)d_out);
}

// Round 5
// 1846.270 us; speedup vs baseline: 8.5834x; 2.1045x over previous
//
#include <hip/hip_runtime.h>

// 4-layer LSTM (15/20/30/40), B=8192, T=512, fp32 in/out. MFMA split-bf16.
// 256 blocks x 512 threads; block owns 32 elements (MFMA N dim).
// Weights as split-bf16 (hi+lo) A-fragments resident in registers.
// Per layer: D = Ah*Bh + Ah*Bl + Al*Bh via v_mfma_f32_32x32x16_bf16 (3 accs).
// Row repack: lane owns 4 CONSECUTIVE units -> h-writes are single b64 stores.
// iv rows XOR-slot-swizzled (T2-style) -> conflict-free b128 B-frag reads.
// Activations: native v_exp_f32 / v_rcp_f32 (no libm expf, no IEEE div).
// 4 barriers/step; x prefetch split issue(ph1)/write(ph2) on w7.

#define NT 512
#define TS 512
#define D1 15
#define D2 20
#define D3 30
#define D4 40

typedef __attribute__((ext_vector_type(8)))  short short8v;
typedef __attribute__((ext_vector_type(16))) float f32x16;
typedef __attribute__((ext_vector_type(4)))  unsigned short ushort4v;

// iv row layouts (ushort offsets within a row; rows XOR-swizzled by slot):
// L1 ROW=64:  x@0..6  bias@7  h1@8..22  (K=23, KT=2)
// L2 ROW=64:  h1@0..14 g@15 bias@16 0@17-19 h2@20..39 (K=40, KT=3)
// L3 ROW=64:  h2@0..19 g@20-23 0@24-27 bias@28 0 h3@32..61 (K=62, KT=4)
// L4 ROW=128: h3@0..29 g@30-31 bias@32 0@33-35 h4@36..75 (K=76, KT=5)
#define ROW1 64
#define ROW2 64
#define ROW3 64
#define ROW4 128
#define PS1 (32*ROW1)
#define PS2 (32*ROW2)
#define PS3 (32*ROW3)
#define PS4 (32*ROW4)
#define B1o 0
#define B2o (B1o + 4*PS1)
#define B3o (B2o + 4*PS2)
#define B4o (B3o + 4*PS3)
#define STOT (B4o + 4*PS4)   // 40960 ushorts = 80 KB
#define SCR_STR 44
#define OB_STR 68

__device__ __forceinline__ float fexp2(float x){ float r; asm("v_exp_f32 %0, %1" : "=v"(r) : "v"(x)); return r; }
__device__ __forceinline__ float frcp(float x){ float r; asm("v_rcp_f32 %0, %1" : "=v"(r) : "v"(x)); return r; }
#define LOG2E 1.4426950408889634f
__device__ __forceinline__ float sigm(float x)  { return frcp(1.0f + fexp2(-LOG2E * x)); }
__device__ __forceinline__ float tanhp(float x) { return 1.0f - 2.0f * frcp(1.0f + fexp2((2.0f*LOG2E) * x)); }

__device__ __forceinline__ unsigned short bfr(float f){
  unsigned u = __float_as_uint(f);
  u += 0x7FFFu + ((u >> 16) & 1u);
  return (unsigned short)(u >> 16);
}
__device__ __forceinline__ float bfv(unsigned short s){
  return __uint_as_float(((unsigned)s) << 16);
}

// Gather one 32-row M-tile of split-bf16 A-fragments.
// Packed row m_local -> gate g = m&3, unit u = 8*mt + 4*((m>>2)&1) + (m>>3)
// => lane (n,up) C regs q=4r+g map to u = 8*mt + 4*up + r (CONSECUTIVE r).
// Col map: k<DIN: Wih; k==BIASK: bih+bhh; H0<=k<H0+DL: Whh[k-H0]; else 0.
template<int KT, int OFF>
__device__ void gatherA(short8v (&ah)[9], short8v (&al)[9], int lane, int mt,
                        const float* Wih, const float* Whh,
                        const float* bih, const float* bhh,
                        int DL, int DIN, int BIASK, int H0) {
  const int upg = lane >> 5, rl = lane & 31;
  const int g = rl & 3;
  const int u = 8*mt + 4*((rl >> 2) & 1) + (rl >> 3);
#pragma unroll
  for (int kt = 0; kt < KT; ++kt) {
#pragma unroll
    for (int j = 0; j < 8; ++j) {
      const int k = kt*16 + upg*8 + j;
      float v = 0.0f;
      if (u < DL) {
        const int srow = g*DL + u;
        if (k < DIN)                      v = Wih[srow*DIN + k];
        else if (k == BIASK)              v = bih[srow] + bhh[srow];
        else if (k >= H0 && k < H0 + DL)  v = Whh[srow*DL + (k - H0)];
      }
      const unsigned short hi = bfr(v);
      const unsigned short lo = bfr(v - bfv(hi));
      ah[OFF+kt][j] = (short)hi;
      al[OFF+kt][j] = (short)lo;
    }
  }
}

// One 32-unit-row tile: 3-acc split-bf16 MFMA + lane-local cell update +
// b64 h-writes (rec = own-layer next-parity, nxt = next-layer current-parity).
template<int KT, int OFF, int ROWC, int ROWN>
__device__ __forceinline__ void doTile(
    const short8v (&ah)[9], const short8v (&al)[9],
    const unsigned short* ivH, const unsigned short* ivL,
    float (&cst)[4], const int u0, const int k0rec,
    unsigned short* recH, unsigned short* recL,
    unsigned short* nxtH, unsigned short* nxtL,
    float* scr4, const int n, const int up) {
  short8v Bh[KT], Bl[KT];
#pragma unroll
  for (int kt = 0; kt < KT; ++kt) {
    const int so = n*ROWC + ((((kt<<1)|up) ^ (n&7)) << 3);
    Bh[kt] = *(const short8v*)(ivH + so);
    Bl[kt] = *(const short8v*)(ivL + so);
  }
  f32x16 a1 = {}, a2 = {}, a3 = {};
#pragma unroll
  for (int kt = 0; kt < KT; ++kt)
    a1 = __builtin_amdgcn_mfma_f32_32x32x16_bf16(ah[OFF+kt], Bh[kt], a1, 0, 0, 0);
#pragma unroll
  for (int kt = 0; kt < KT; ++kt)
    a2 = __builtin_amdgcn_mfma_f32_32x32x16_bf16(ah[OFF+kt], Bl[kt], a2, 0, 0, 0);
#pragma unroll
  for (int kt = 0; kt < KT; ++kt)
    a3 = __builtin_amdgcn_mfma_f32_32x32x16_bf16(al[OFF+kt], Bh[kt], a3, 0, 0, 0);
  const int ub = u0 + (up << 2);
  ushort4v vh, vl;
  float hv[4];
#pragma unroll
  for (int r = 0; r < 4; ++r) {
    const float gi = a1[4*r+0] + a2[4*r+0] + a3[4*r+0];
    const float gf = a1[4*r+1] + a2[4*r+1] + a3[4*r+1];
    const float gg = a1[4*r+2] + a2[4*r+2] + a3[4*r+2];
    const float go = a1[4*r+3] + a2[4*r+3] + a3[4*r+3];
    const float ii = sigm(gi), ff = sigm(gf), g2 = tanhp(gg), oo = sigm(go);
    cst[r] = fmaf(ff, cst[r], ii * g2);
    const float h = oo * tanhp(cst[r]);
    hv[r] = h;
    const unsigned short hb = bfr(h);
    vh[r] = hb;
    vl[r] = bfr(h - bfv(hb));
  }
  { const int k = k0rec + ub;
    const int a = n*ROWC + (((k>>3) ^ (n&7)) << 3) + (k & 7);
    *(ushort4v*)(recH + a) = vh;
    *(ushort4v*)(recL + a) = vl; }
  if (nxtH) {
    const int k = ub;
    const int a = n*ROWN + (((k>>3) ^ (n&7)) << 3) + (k & 7);
    *(ushort4v*)(nxtH + a) = vh;
    *(ushort4v*)(nxtL + a) = vl; }
  if (scr4) {
    *(float4*)(scr4 + n*SCR_STR + ub) = make_float4(hv[0], hv[1], hv[2], hv[3]); }
}

__global__ void __launch_bounds__(NT, 1)
lstm_mfma(const float* __restrict__ x,
          const float* __restrict__ Wih1, const float* __restrict__ Whh1,
          const float* __restrict__ bih1, const float* __restrict__ bhh1,
          const float* __restrict__ Wih2, const float* __restrict__ Whh2,
          const float* __restrict__ bih2, const float* __restrict__ bhh2,
          const float* __restrict__ Wih3, const float* __restrict__ Whh3,
          const float* __restrict__ bih3, const float* __restrict__ bhh3,
          const float* __restrict__ Wih4, const float* __restrict__ Whh4,
          const float* __restrict__ bih4, const float* __restrict__ bhh4,
          const float* __restrict__ Wl, const float* __restrict__ bl,
          float* __restrict__ out) {
  __shared__ __align__(16) unsigned short S[STOT];
  __shared__ __align__(16) float scr[32*SCR_STR];
  __shared__ __align__(16) float obuf[32*OB_STR];

  const int tid = threadIdx.x;
  const int wv = tid >> 6, lane = tid & 63;
  const int n = lane & 31, up = lane >> 5;
  const long gb = (long)blockIdx.x * 32;

  for (int i = tid; i < STOT/2; i += NT) ((unsigned*)S)[i] = 0u;
  __syncthreads();
  // bias slots (hi plane = 0x3F80), both parities; L1 bias rides x-staging
  if (tid < 32) {
#pragma unroll
    for (int par = 0; par < 2; ++par) {
      S[B2o + par*2*PS2 + tid*ROW2 + (((16>>3) ^ (tid&7)) << 3) + (16 & 7)] = 0x3F80;
      S[B3o + par*2*PS3 + tid*ROW3 + (((28>>3) ^ (tid&7)) << 3) + (28 & 7)] = 0x3F80;
      S[B4o + par*2*PS4 + tid*ROW4 + (((32>>3) ^ (tid&7)) << 3) + (32 & 7)] = 0x3F80;
    }
  }

  // ---- one-time A-fragment gather ----
  short8v ah[9], al[9];
  if      (wv == 0) { gatherA<2,0>(ah,al,lane,0,Wih1,Whh1,bih1,bhh1,D1,7,7,8);
                      gatherA<4,2>(ah,al,lane,0,Wih3,Whh3,bih3,bhh3,D3,20,28,32); }
  else if (wv == 1) { gatherA<2,0>(ah,al,lane,1,Wih1,Whh1,bih1,bhh1,D1,7,7,8);
                      gatherA<4,2>(ah,al,lane,1,Wih3,Whh3,bih3,bhh3,D3,20,28,32); }
  else if (wv == 2) { gatherA<3,0>(ah,al,lane,0,Wih2,Whh2,bih2,bhh2,D2,15,16,20);
                      gatherA<4,3>(ah,al,lane,2,Wih3,Whh3,bih3,bhh3,D3,20,28,32); }
  else if (wv == 3) { gatherA<3,0>(ah,al,lane,1,Wih2,Whh2,bih2,bhh2,D2,15,16,20);
                      gatherA<5,3>(ah,al,lane,4,Wih4,Whh4,bih4,bhh4,D4,30,32,36); }
  else if (wv == 4) { gatherA<3,0>(ah,al,lane,2,Wih2,Whh2,bih2,bhh2,D2,15,16,20);
                      gatherA<5,3>(ah,al,lane,0,Wih4,Whh4,bih4,bhh4,D4,30,32,36); }
  else if (wv == 5) { gatherA<4,0>(ah,al,lane,3,Wih3,Whh3,bih3,bhh3,D3,20,28,32);
                      gatherA<5,4>(ah,al,lane,1,Wih4,Whh4,bih4,bhh4,D4,30,32,36); }
  else if (wv == 6) { gatherA<5,0>(ah,al,lane,2,Wih4,Whh4,bih4,bhh4,D4,30,32,36); }
  else              { gatherA<5,0>(ah,al,lane,3,Wih4,Whh4,bih4,bhh4,D4,30,32,36); }

  // output weights (w6)
  float wlv[20];
#pragma unroll
  for (int j = 0; j < 20; ++j) wlv[j] = Wl[up*20 + j];
  const float blv = bl[0];

  float c0s[4] = {0,0,0,0}, c1s[4] = {0,0,0,0};

  // x(0) preload into parity-0 L1 rows (w7): k 0..3 (up-half 0) / 4..6+bias
  if (wv == 7) {
    const int el = lane >> 1, half = lane & 1;
    const float* xa = x + (gb + el)*(TS*7);
    unsigned short* dH = S + B1o + el*ROW1 + ((0 ^ (el&7)) << 3) + half*4;
    unsigned short* dL = dH + PS1;
    ushort4v vh, vl;
    if (half == 0) {
#pragma unroll
      for (int j = 0; j < 4; ++j) { float v = xa[j]; unsigned short h = bfr(v);
        vh[j] = h; vl[j] = bfr(v - bfv(h)); }
    } else {
#pragma unroll
      for (int j = 0; j < 3; ++j) { float v = xa[4+j]; unsigned short h = bfr(v);
        vh[j] = h; vl[j] = bfr(v - bfv(h)); }
      vh[3] = 0x3F80; vl[3] = 0;
    }
    *(ushort4v*)dH = vh; *(ushort4v*)dL = vl;
  }
  __syncthreads();

#pragma unroll 1
  for (int t = 0; t < TS; ++t) {
    const int cb = t & 1, nb = cb ^ 1;
    unsigned short* i1H  = S + B1o + cb*2*PS1;  unsigned short* i1L  = i1H + PS1;
    unsigned short* i1Hn = S + B1o + nb*2*PS1;  unsigned short* i1Ln = i1Hn + PS1;
    unsigned short* i2H  = S + B2o + cb*2*PS2;  unsigned short* i2L  = i2H + PS2;
    unsigned short* i2Hn = S + B2o + nb*2*PS2;  unsigned short* i2Ln = i2Hn + PS2;
    unsigned short* i3H  = S + B3o + cb*2*PS3;  unsigned short* i3L  = i3H + PS3;
    unsigned short* i3Hn = S + B3o + nb*2*PS3;  unsigned short* i3Ln = i3Hn + PS3;
    unsigned short* i4H  = S + B4o + cb*2*PS4;  unsigned short* i4L  = i4H + PS4;
    unsigned short* i4Hn = S + B4o + nb*2*PS4;  unsigned short* i4Ln = i4Hn + PS4;

    float xv0 = 0.f, xv1 = 0.f, xv2 = 0.f, xv3 = 0.f;

    // ---------- phase 1: L1 (w0,w1) | y(t-1)+flush (w6) | x issue (w7) -----
    if      (wv == 0) doTile<2,0,ROW1,ROW2>(ah,al, i1H,i1L, c0s, 0, 8,
                                            i1Hn,i1Ln, i2H,i2L, nullptr, n, up);
    else if (wv == 1) doTile<2,0,ROW1,ROW2>(ah,al, i1H,i1L, c0s, 8, 8,
                                            i1Hn,i1Ln, i2H,i2L, nullptr, n, up);
    else if (wv == 6) {
      if (t > 0) {
        const float* sp = scr + n*SCR_STR + up*20;
        float part = 0.0f;
#pragma unroll
        for (int q = 0; q < 5; ++q) {
          const float4 v = *(const float4*)(sp + 4*q);
          part = fmaf(v.x, wlv[4*q+0], part);
          part = fmaf(v.y, wlv[4*q+1], part);
          part = fmaf(v.z, wlv[4*q+2], part);
          part = fmaf(v.w, wlv[4*q+3], part);
        }
        part += __shfl_xor(part, 32);
        if (lane < 32) obuf[n*OB_STR + ((t-1) & 63)] = part + blv;
        if ((t & 63) == 0) {
          __asm__ volatile("s_waitcnt lgkmcnt(0)" ::: "memory");
#pragma unroll
          for (int it = 0; it < 8; ++it) {
            const int row = it*4 + (lane >> 4), col = (lane & 15) << 2;
            const float4 v = *(const float4*)(obuf + row*OB_STR + col);
            *(float4*)(out + (gb + row)*TS + (t - 64) + col) = v;
          }
        }
      }
    }
    else if (wv == 7) {
      if (t + 1 < TS) {
        const float* xa = x + (gb + (lane>>1))*(TS*7) + (t+1)*7 + (lane&1)*4;
        xv0 = xa[0]; xv1 = xa[1]; xv2 = xa[2];
        if ((lane & 1) == 0) xv3 = xa[3];
      }
    }
    __syncthreads();

    // ---------- phase 2: L2 (w2,w3,w4) | x convert+write (w7) --------------
    if      (wv == 2) doTile<3,0,ROW2,ROW3>(ah,al, i2H,i2L, c0s, 0,  20,
                                            i2Hn,i2Ln, i3H,i3L, nullptr, n, up);
    else if (wv == 3) doTile<3,0,ROW2,ROW3>(ah,al, i2H,i2L, c0s, 8,  20,
                                            i2Hn,i2Ln, i3H,i3L, nullptr, n, up);
    else if (wv == 4) doTile<3,0,ROW2,ROW3>(ah,al, i2H,i2L, c0s, 16, 20,
                                            i2Hn,i2Ln, i3H,i3L, nullptr, n, up);
    else if (wv == 7) {
      if (t + 1 < TS) {
        const int el = lane >> 1, half = lane & 1;
        unsigned short* dH = i1Hn + el*ROW1 + ((0 ^ (el&7)) << 3) + half*4;
        unsigned short* dL = dH + PS1;
        ushort4v vh, vl;
        unsigned short h0 = bfr(xv0), h1 = bfr(xv1), h2 = bfr(xv2);
        vh[0] = h0; vl[0] = bfr(xv0 - bfv(h0));
        vh[1] = h1; vl[1] = bfr(xv1 - bfv(h1));
        vh[2] = h2; vl[2] = bfr(xv2 - bfv(h2));
        if (half == 0) { unsigned short h3 = bfr(xv3); vh[3] = h3; vl[3] = bfr(xv3 - bfv(h3)); }
        else           { vh[3] = 0x3F80; vl[3] = 0; }
        *(ushort4v*)dH = vh; *(ushort4v*)dL = vl;
      }
    }
    __syncthreads();

    // ---------- phase 3: L3 (w0,w1,w2,w5) ----------------------------------
    if      (wv == 0) doTile<4,2,ROW3,ROW4>(ah,al, i3H,i3L, c1s, 0,  32,
                                            i3Hn,i3Ln, i4H,i4L, nullptr, n, up);
    else if (wv == 1) doTile<4,2,ROW3,ROW4>(ah,al, i3H,i3L, c1s, 8,  32,
                                            i3Hn,i3Ln, i4H,i4L, nullptr, n, up);
    else if (wv == 2) doTile<4,3,ROW3,ROW4>(ah,al, i3H,i3L, c1s, 16, 32,
                                            i3Hn,i3Ln, i4H,i4L, nullptr, n, up);
    else if (wv == 5) doTile<4,0,ROW3,ROW4>(ah,al, i3H,i3L, c0s, 24, 32,
                                            i3Hn,i3Ln, i4H,i4L, nullptr, n, up);
    __syncthreads();

    // ---------- phase 4: L4 (w3,w4,w5,w6,w7) -------------------------------
    if      (wv == 3) doTile<5,3,ROW4,ROW4>(ah,al, i4H,i4L, c1s, 32, 36,
                                            i4Hn,i4Ln, nullptr,nullptr, scr, n, up);
    else if (wv == 4) doTile<5,3,ROW4,ROW4>(ah,al, i4H,i4L, c1s, 0,  36,
                                            i4Hn,i4Ln, nullptr,nullptr, scr, n, up);
    else if (wv == 5) doTile<5,4,ROW4,ROW4>(ah,al, i4H,i4L, c1s, 8,  36,
                                            i4Hn,i4Ln, nullptr,nullptr, scr, n, up);
    else if (wv == 6) doTile<5,0,ROW4,ROW4>(ah,al, i4H,i4L, c0s, 16, 36,
                                            i4Hn,i4Ln, nullptr,nullptr, scr, n, up);
    else if (wv == 7) doTile<5,0,ROW4,ROW4>(ah,al, i4H,i4L, c0s, 24, 36,
                                            i4Hn,i4Ln, nullptr,nullptr, scr, n, up);
    __syncthreads();
  }

  // ---- tail: y(511) + final flush (w6) ----
  if (wv == 6) {
    const float* sp = scr + n*SCR_STR + up*20;
    float part = 0.0f;
#pragma unroll
    for (int q = 0; q < 5; ++q) {
      const float4 v = *(const float4*)(sp + 4*q);
      part = fmaf(v.x, wlv[4*q+0], part);
      part = fmaf(v.y, wlv[4*q+1], part);
      part = fmaf(v.z, wlv[4*q+2], part);
      part = fmaf(v.w, wlv[4*q+3], part);
    }
    part += __shfl_xor(part, 32);
    if (lane < 32) obuf[n*OB_STR + 63] = part + blv;
    __asm__ volatile("s_waitcnt lgkmcnt(0)" ::: "memory");
#pragma unroll
    for (int it = 0; it < 8; ++it) {
      const int row = it*4 + (lane >> 4), col = (lane & 15) << 2;
      const float4 v = *(const float4*)(obuf + row*OB_STR + col);
      *(float4*)(out + (gb + row)*TS + 448 + col) = v;
    }
  }
}

extern "C" void kernel_launch(void* const* d_in, const int* in_sizes, int n_in,
                              void* d_out, int out_size, void* d_ws, size_t ws_size,
                              hipStream_t stream) {
  lstm_mfma<<<dim3(8192/32), dim3(NT), 0, stream>>>(
      (const float*)d_in[0],
      (const float*)d_in[1],  (const float*)d_in[2],  (const float*)d_in[3],  (const float*)d_in[4],
      (const float*)d_in[5],  (const float*)d_in[6],  (const float*)d_in[7],  (const float*)d_in[8],
      (const float*)d_in[9],  (const float*)d_in[10], (const float*)d_in[11], (const float*)d_in[12],
      (const float*)d_in[13], (const float*)d_in[14], (const float*)d_in[15], (const float*)d_in[16],
      (const float*)d_in[17], (const float*)d_in[18],
      (float*)d_out);
}

// Round 6
// 991.228 us; speedup vs baseline: 15.9875x; 1.8626x over previous
//
#include <hip/hip_runtime.h>

// 4-layer LSTM (15/20/30/40), B=8192, T=512, fp32 in/out. MFMA split-bf16,
// SOFTWARE-PIPELINED across layers/time: period P runs L1@t=P, L2@P-1,
// L3@P-2, L4@P-3, y@P-4 concurrently on different waves; ONE barrier per
// period; all reads parity P&1, all writes parity (P+1)&1.
// LDS B-operands in frag-major layout (slot=k>>3, x element): ds_read_b128
// is lane-contiguous -> conflict-free. Weights = split-bf16 (hi+lo) A-frags
// in registers; D = Ah*Bh + Ah*Bl + Al*Bh chained into ONE accumulator.
// Activations on v_exp_f32/v_rcp_f32; h->bf16 hi/lo via v_cvt_pk_bf16_f32.

#define NT 512
#define TS 512
#define D1 15
#define D2 20
#define D3 30
#define D4 40

typedef __attribute__((ext_vector_type(8)))  short short8v;
typedef __attribute__((ext_vector_type(16))) float f32x16;

// frag-major LDS: addr(layer, slot=k>>3, n, j=k&7) = Lo + (slot*32 + n)*8 + j
// K layouts:
// L1 (4 slots, K=32):  x@0..6  bias@7  h1@8..22
// L2 (6 slots, K=48):  h1@0..14  bias@16  h2@20..39
// L3 (8 slots, K=64):  h2@0..19  bias@28  h3@32..61
// L4 (10 slots, K=80): h3@0..29  bias@32  h4@36..75
#define L1o 0
#define L2o 1024
#define L3o 2560
#define L4o 4608
#define PPSZ 7168   // ushorts per (parity, plane)

__device__ __forceinline__ float fexp2(float x){ float r; asm("v_exp_f32 %0, %1" : "=v"(r) : "v"(x)); return r; }
__device__ __forceinline__ float frcp(float x){ float r; asm("v_rcp_f32 %0, %1" : "=v"(r) : "v"(x)); return r; }
#define LOG2E 1.4426950408889634f
__device__ __forceinline__ float sigm(float x)  { return frcp(1.0f + fexp2(-LOG2E * x)); }
__device__ __forceinline__ float tanhp(float x) { return 1.0f - 2.0f * frcp(1.0f + fexp2((2.0f*LOG2E) * x)); }

// packed bf16 convert: r.lo16 = bf16(a), r.hi16 = bf16(b)
__device__ __forceinline__ unsigned cvtpk(float a, float b){
  unsigned r; asm("v_cvt_pk_bf16_f32 %0, %1, %2" : "=v"(r) : "v"(a), "v"(b)); return r;
}

// scalar f32 -> bf16 RNE (init-time only)
__device__ __forceinline__ unsigned short bfr(float f){
  unsigned u = __float_as_uint(f);
  u += 0x7FFFu + ((u >> 16) & 1u);
  return (unsigned short)(u >> 16);
}
__device__ __forceinline__ float bfv(unsigned short s){
  return __uint_as_float(((unsigned)s) << 16);
}

// Gather one 32-row M-tile of split-bf16 A-fragments from global fp32.
// A-row m: gate g = m&3, unit u = 8*mt + 4*((m>>2)&1) + (m>>3)  (so the lane's
// C regs q=4r+g cover 4 CONSECUTIVE units ub0..ub0+3, ub0 = 8*mt + 4*up).
// k map: k<DIN: Wih; k==BIASK: bih+bhh; H0<=k<H0+DL: Whh[k-H0]; else 0.
template<int KT, int OFF>
__device__ void gatherA(short8v (&ah)[10], short8v (&al)[10], int lane, int mt,
                        const float* Wih, const float* Whh,
                        const float* bih, const float* bhh,
                        int DL, int DIN, int BIASK, int H0) {
  const int upg = lane >> 5, rl = lane & 31;
  const int g = rl & 3;
  const int u = 8*mt + 4*((rl >> 2) & 1) + (rl >> 3);
#pragma unroll
  for (int kt = 0; kt < KT; ++kt) {
#pragma unroll
    for (int j = 0; j < 8; ++j) {
      const int k = kt*16 + upg*8 + j;
      float v = 0.0f;
      if (u < DL) {
        const int srow = g*DL + u;
        if (k < DIN)                      v = Wih[srow*DIN + k];
        else if (k == BIASK)              v = bih[srow] + bhh[srow];
        else if (k >= H0 && k < H0 + DL)  v = Whh[srow*DL + (k - H0)];
      }
      const unsigned short hi = bfr(v);
      const unsigned short lo = bfr(v - bfv(hi));
      ah[OFF+kt][j] = (short)hi;
      al[OFF+kt][j] = (short)lo;
    }
  }
}

// One 32-row tile: single-acc 3-term MFMA chain + lane-local cell update +
// b64 hi/lo h writes into rec (own layer, write parity) and nxt (next layer).
template<int KT, int OFF>
__device__ __forceinline__ void doTile(
    const short8v (&ah)[10], const short8v (&al)[10],
    const unsigned short* bH, const unsigned short* bL,
    float (&cst)[4], const int u0t, const int recK0,
    unsigned short* recH, unsigned short* recL,
    unsigned short* nxtH, unsigned short* nxtL,
    float* scrp, const int n, const int up) {
  short8v Bh[KT], Bl[KT];
#pragma unroll
  for (int kt = 0; kt < KT; ++kt) {
    const int a = ((((kt<<1)|up)*32 + n) << 3);
    Bh[kt] = *(const short8v*)(bH + a);
    Bl[kt] = *(const short8v*)(bL + a);
  }
  f32x16 acc = {};
#pragma unroll
  for (int kt = 0; kt < KT; ++kt)
    acc = __builtin_amdgcn_mfma_f32_32x32x16_bf16(ah[OFF+kt], Bh[kt], acc, 0, 0, 0);
#pragma unroll
  for (int kt = 0; kt < KT; ++kt)
    acc = __builtin_amdgcn_mfma_f32_32x32x16_bf16(ah[OFF+kt], Bl[kt], acc, 0, 0, 0);
#pragma unroll
  for (int kt = 0; kt < KT; ++kt)
    acc = __builtin_amdgcn_mfma_f32_32x32x16_bf16(al[OFF+kt], Bh[kt], acc, 0, 0, 0);
  // C layout: col = lane&31 = element n, row = (q&3)+8*(q>>2)+4*up
  float h[4];
#pragma unroll
  for (int r = 0; r < 4; ++r) {
    const float ii = sigm(acc[4*r+0]);
    const float ff = sigm(acc[4*r+1]);
    const float g2 = tanhp(acc[4*r+2]);
    const float oo = sigm(acc[4*r+3]);
    cst[r] = fmaf(ff, cst[r], ii * g2);
    h[r] = oo * tanhp(cst[r]);
  }
  const unsigned pa = cvtpk(h[0], h[1]);
  const unsigned pb = cvtpk(h[2], h[3]);
  const float f0 = h[0] - __uint_as_float(pa << 16);
  const float f1 = h[1] - __uint_as_float(pa & 0xFFFF0000u);
  const float f2 = h[2] - __uint_as_float(pb << 16);
  const float f3 = h[3] - __uint_as_float(pb & 0xFFFF0000u);
  uint2 vh; vh.x = pa;            vh.y = pb;
  uint2 vl; vl.x = cvtpk(f0, f1); vl.y = cvtpk(f2, f3);
  const int ub0 = u0t + (up << 2);
  { const int k0 = recK0 + ub0;
    const int a = (((k0 >> 3)*32 + n) << 3) + (k0 & 7);
    *(uint2*)(recH + a) = vh;  *(uint2*)(recL + a) = vl; }
  if (nxtH) {
    const int a = (((ub0 >> 3)*32 + n) << 3) + (ub0 & 7);
    *(uint2*)(nxtH + a) = vh;  *(uint2*)(nxtL + a) = vl; }
  if (scrp) *(float4*)(scrp + n*44 + ub0) = make_float4(h[0], h[1], h[2], h[3]);
}

// x staging: slot 0 of L1, k = half*4 + j (half==1: {x4,x5,x6,bias=1.0})
__device__ __forceinline__ void writeX(unsigned short* H, unsigned short* L,
                                       int el, int half,
                                       float v0, float v1, float v2, float v3) {
  const unsigned pa = cvtpk(v0, v1), pb = cvtpk(v2, v3);
  const float f0 = v0 - __uint_as_float(pa << 16);
  const float f1 = v1 - __uint_as_float(pa & 0xFFFF0000u);
  const float f2 = v2 - __uint_as_float(pb << 16);
  const float f3 = v3 - __uint_as_float(pb & 0xFFFF0000u);
  uint2 vh; vh.x = pa;            vh.y = pb;
  uint2 vl; vl.x = cvtpk(f0, f1); vl.y = cvtpk(f2, f3);
  const int a = (el << 3) + (half << 2);
  *(uint2*)(H + a) = vh;
  *(uint2*)(L + a) = vl;
}

__global__ void __launch_bounds__(NT, 1)
lstm_pipe(const float* __restrict__ x,
          const float* __restrict__ Wih1, const float* __restrict__ Whh1,
          const float* __restrict__ bih1, const float* __restrict__ bhh1,
          const float* __restrict__ Wih2, const float* __restrict__ Whh2,
          const float* __restrict__ bih2, const float* __restrict__ bhh2,
          const float* __restrict__ Wih3, const float* __restrict__ Whh3,
          const float* __restrict__ bih3, const float* __restrict__ bhh3,
          const float* __restrict__ Wih4, const float* __restrict__ Whh4,
          const float* __restrict__ bih4, const float* __restrict__ bhh4,
          const float* __restrict__ Wl, const float* __restrict__ bl,
          float* __restrict__ out) {
  __shared__ __align__(16) unsigned short S[2*2*PPSZ];   // [parity][plane][..]
  __shared__ __align__(16) float scrA[2*32*44];           // h4 fp32, 2 parities
  __shared__ __align__(16) float obuf[32*68];
  __shared__ float wlS[41];

  const int tid  = threadIdx.x;
  const int wv   = tid >> 6, lane = tid & 63;
  const int n    = lane & 31, up = lane >> 5;
  const long gb  = (long)blockIdx.x * 32;

  // ---- init: zero all buffers ----
  for (int i = tid; i < 2*2*PPSZ/2; i += NT) ((unsigned*)S)[i] = 0u;
  if (tid < 41) wlS[tid] = (tid < 40) ? Wl[tid] : bl[0];
  __syncthreads();
  // bias slots (hi plane), both parities; L1 bias rides x-staging
  if (tid < 64) {
    const int par = tid >> 5, nn = tid & 31;
    unsigned short* H = S + (par*2 + 0)*PPSZ;
    H[L2o + (2*32 + nn)*8 + 0] = 0x3F80;   // L2 k16
    H[L3o + (3*32 + nn)*8 + 4] = 0x3F80;   // L3 k28
    H[L4o + (4*32 + nn)*8 + 0] = 0x3F80;   // L4 k32
  }
  // x(0) -> parity 0 (w6 = x role)
  if (wv == 6) {
    const int el = lane >> 1, half = lane & 1;
    const float* xa = x + (gb + el)*(TS*7) + (half << 2);
    const float v0 = xa[0], v1 = xa[1], v2 = xa[2];
    const float v3 = half ? 1.0f : xa[3];
    writeX(S + 0*PPSZ + L1o, S + 1*PPSZ + L1o, el, half, v0, v1, v2, v3);
  }

  // ---- one-time A-fragment gather (registers) ----
  short8v ah[10], al[10];
  if      (wv == 0) { gatherA<2,0>(ah,al,lane,0,Wih1,Whh1,bih1,bhh1,D1,7,7,8);
                      gatherA<4,2>(ah,al,lane,0,Wih3,Whh3,bih3,bhh3,D3,20,28,32); }
  else if (wv == 1) { gatherA<2,0>(ah,al,lane,1,Wih1,Whh1,bih1,bhh1,D1,7,7,8);
                      gatherA<4,2>(ah,al,lane,1,Wih3,Whh3,bih3,bhh3,D3,20,28,32); }
  else if (wv == 2) { gatherA<3,0>(ah,al,lane,0,Wih2,Whh2,bih2,bhh2,D2,15,16,20);
                      gatherA<4,3>(ah,al,lane,2,Wih3,Whh3,bih3,bhh3,D3,20,28,32); }
  else if (wv == 3) { gatherA<3,0>(ah,al,lane,1,Wih2,Whh2,bih2,bhh2,D2,15,16,20);
                      gatherA<4,3>(ah,al,lane,3,Wih3,Whh3,bih3,bhh3,D3,20,28,32); }
  else if (wv == 4) { gatherA<3,0>(ah,al,lane,2,Wih2,Whh2,bih2,bhh2,D2,15,16,20);
                      gatherA<5,3>(ah,al,lane,0,Wih4,Whh4,bih4,bhh4,D4,30,32,36); }
  else if (wv == 5) { gatherA<5,0>(ah,al,lane,1,Wih4,Whh4,bih4,bhh4,D4,30,32,36); }
  else if (wv == 6) { gatherA<5,0>(ah,al,lane,2,Wih4,Whh4,bih4,bhh4,D4,30,32,36); }
  else              { gatherA<5,0>(ah,al,lane,3,Wih4,Whh4,bih4,bhh4,D4,30,32,36);
                      gatherA<5,5>(ah,al,lane,4,Wih4,Whh4,bih4,bhh4,D4,30,32,36); }

  float c0s[4] = {0,0,0,0}, c1s[4] = {0,0,0,0};
  __syncthreads();

  // ---- pipelined main loop: L1@P, L2@P-1, L3@P-2, L4@P-3, y@P-4 ----
#pragma unroll 1
  for (int P = 0; P < TS + 4; ++P) {
    const int cur = P & 1;
    const unsigned short* rH = S + (cur*2 + 0)*PPSZ;
    const unsigned short* rL = S + (cur*2 + 1)*PPSZ;
    unsigned short* wH = S + ((cur^1)*2 + 0)*PPSZ;
    unsigned short* wL = S + ((cur^1)*2 + 1)*PPSZ;
    float* scrW = scrA + (cur^1)*(32*44);

    float xv0 = 0.f, xv1 = 0.f, xv2 = 0.f, xv3 = 0.f;
    if (wv == 6 && P <= TS - 2) {   // issue x(P+1) loads early
      const float* xa = x + (gb + (lane >> 1))*(TS*7) + (P + 1)*7 + ((lane & 1) << 2);
      xv0 = xa[0]; xv1 = xa[1]; xv2 = xa[2];
      xv3 = (lane & 1) ? 1.0f : xa[3];
    }

    if (wv == 0) {
      if (P <= TS-1)           doTile<2,0>(ah,al, rH+L1o,rL+L1o, c0s, 0,  8,
                                           wH+L1o,wL+L1o, wH+L2o,wL+L2o, nullptr, n, up);
      if (P >= 2 && P <= TS+1) doTile<4,2>(ah,al, rH+L3o,rL+L3o, c1s, 0,  32,
                                           wH+L3o,wL+L3o, wH+L4o,wL+L4o, nullptr, n, up);
    } else if (wv == 1) {
      if (P <= TS-1)           doTile<2,0>(ah,al, rH+L1o,rL+L1o, c0s, 8,  8,
                                           wH+L1o,wL+L1o, wH+L2o,wL+L2o, nullptr, n, up);
      if (P >= 2 && P <= TS+1) doTile<4,2>(ah,al, rH+L3o,rL+L3o, c1s, 8,  32,
                                           wH+L3o,wL+L3o, wH+L4o,wL+L4o, nullptr, n, up);
    } else if (wv == 2) {
      if (P >= 1 && P <= TS)   doTile<3,0>(ah,al, rH+L2o,rL+L2o, c0s, 0,  20,
                                           wH+L2o,wL+L2o, wH+L3o,wL+L3o, nullptr, n, up);
      if (P >= 2 && P <= TS+1) doTile<4,3>(ah,al, rH+L3o,rL+L3o, c1s, 16, 32,
                                           wH+L3o,wL+L3o, wH+L4o,wL+L4o, nullptr, n, up);
    } else if (wv == 3) {
      if (P >= 1 && P <= TS)   doTile<3,0>(ah,al, rH+L2o,rL+L2o, c0s, 8,  20,
                                           wH+L2o,wL+L2o, wH+L3o,wL+L3o, nullptr, n, up);
      if (P >= 2 && P <= TS+1) doTile<4,3>(ah,al, rH+L3o,rL+L3o, c1s, 24, 32,
                                           wH+L3o,wL+L3o, wH+L4o,wL+L4o, nullptr, n, up);
    } else if (wv == 4) {
      if (P >= 1 && P <= TS)   doTile<3,0>(ah,al, rH+L2o,rL+L2o, c0s, 16, 20,
                                           wH+L2o,wL+L2o, wH+L3o,wL+L3o, nullptr, n, up);
      if (P >= 3 && P <= TS+2) doTile<5,3>(ah,al, rH+L4o,rL+L4o, c1s, 0,  36,
                                           wH+L4o,wL+L4o, nullptr,nullptr, scrW, n, up);
    } else if (wv == 5) {
      if (P >= 3 && P <= TS+2) doTile<5,0>(ah,al, rH+L4o,rL+L4o, c0s, 8,  36,
                                           wH+L4o,wL+L4o, nullptr,nullptr, scrW, n, up);
      if (P >= 4) {   // y(P-4)
        const int ty = P - 4;
        const float* sp = scrA + cur*(32*44) + n*44 + up*20;
        float part = 0.0f;
#pragma unroll
        for (int q = 0; q < 5; ++q) {
          const float4 v = *(const float4*)(sp + 4*q);
          const float4 w = *(const float4*)(wlS + up*20 + 4*q);
          part = fmaf(v.x, w.x, fmaf(v.y, w.y, fmaf(v.z, w.z, fmaf(v.w, w.w, part))));
        }
        part += __shfl_xor(part, 32);
        if (lane < 32) obuf[n*68 + (ty & 63)] = part + wlS[40];
        if ((ty & 63) == 63) {
#pragma unroll
          for (int it = 0; it < 8; ++it) {
            const int row = it*4 + (lane >> 4), col = (lane & 15) << 2;
            const float4 v = *(const float4*)(obuf + row*68 + col);
            *(float4*)(out + (gb + row)*TS + (ty - 63) + col) = v;
          }
        }
      }
    } else if (wv == 6) {
      if (P >= 3 && P <= TS+2) doTile<5,0>(ah,al, rH+L4o,rL+L4o, c0s, 16, 36,
                                           wH+L4o,wL+L4o, nullptr,nullptr, scrW, n, up);
      if (P <= TS-2)
        writeX(wH + L1o, wL + L1o, lane >> 1, lane & 1, xv0, xv1, xv2, xv3);
    } else {  // wv == 7
      if (P >= 3 && P <= TS+2) {
        doTile<5,0>(ah,al, rH+L4o,rL+L4o, c0s, 24, 36,
                    wH+L4o,wL+L4o, nullptr,nullptr, scrW, n, up);
        doTile<5,5>(ah,al, rH+L4o,rL+L4o, c1s, 32, 36,
                    wH+L4o,wL+L4o, nullptr,nullptr, scrW, n, up);
      }
    }
    __syncthreads();
  }
}

extern "C" void kernel_launch(void* const* d_in, const int* in_sizes, int n_in,
                              void* d_out, int out_size, void* d_ws, size_t ws_size,
                              hipStream_t stream) {
  lstm_pipe<<<dim3(8192/32), dim3(NT), 0, stream>>>(
      (const float*)d_in[0],
      (const float*)d_in[1],  (const float*)d_in[2],  (const float*)d_in[3],  (const float*)d_in[4],
      (const float*)d_in[5],  (const float*)d_in[6],  (const float*)d_in[7],  (const float*)d_in[8],
      (const float*)d_in[9],  (const float*)d_in[10], (const float*)d_in[11], (const float*)d_in[12],
      (const float*)d_in[13], (const float*)d_in[14], (const float*)d_in[15], (const float*)d_in[16],
      (const float*)d_in[17], (const float*)d_in[18],
      (float*)d_out);
}

// Round 7
// 786.481 us; speedup vs baseline: 20.1495x; 1.2603x over previous
//
#include <hip/hip_runtime.h>

// 4-layer LSTM (15/20/30/40), B=8192, T=512, fp32 in/out. MFMA split-bf16,
// layer-pipelined: period P runs L1@t=P, L2@P-1, L3@P-2, L4@P-3, y@P-4.
// NEW vs r6: 1024 threads = 16 waves, ONE tile per wave (14 tiles + y + x),
// 4 waves/SIMD; h stored ONCE per parity (shared slot maps + ONE/ZERO slots).
// One barrier per period. Weights = split-bf16 hi/lo A-frags in registers;
// D = Ah*Bh + Ah*Bl + Al*Bh chained into one accumulator.

#define NT 1024
#define TS 512

typedef __attribute__((ext_vector_type(8)))  short short8v;
typedef __attribute__((ext_vector_type(16))) float f32x16;

// LDS (ushort units): 4 planes [parity(2) x hi/lo] of 3840:
//   region offsets within a plane: SX=0(1 slot) H1=256(2) H2=768(3)
//   H3=1536(4) H4=2560(5); slot = 256 ush = 32 elem x 8 k.
// plane(par,q) base = par*7680 + q*3840. Shared tail: ONE@15360 (0x3F80),
// Z@15616, and [19200,19712) zeros so ptr+3840 of ONE/Z reads zeros.
#define RH1 256
#define RH2 768
#define RH3 1536
#define RH4 2560
#define ONEO 15360
#define ZO   15616
#define STOTU 19712

__device__ __forceinline__ float fexp2(float x){ float r; asm("v_exp_f32 %0, %1" : "=v"(r) : "v"(x)); return r; }
__device__ __forceinline__ float frcp(float x){ float r; asm("v_rcp_f32 %0, %1" : "=v"(r) : "v"(x)); return r; }
#define LOG2E 1.4426950408889634f
__device__ __forceinline__ float sigm(float x)  { return frcp(1.0f + fexp2(-LOG2E * x)); }
__device__ __forceinline__ float tanhp(float x) { return 1.0f - 2.0f * frcp(1.0f + fexp2((2.0f*LOG2E) * x)); }

__device__ __forceinline__ unsigned cvtpk(float a, float b){
  unsigned r; asm("v_cvt_pk_bf16_f32 %0, %1, %2" : "=v"(r) : "v"(a), "v"(b)); return r;
}
__device__ __forceinline__ unsigned short bfr(float f){
  unsigned u = __float_as_uint(f);
  u += 0x7FFFu + ((u >> 16) & 1u);
  return (unsigned short)(u >> 16);
}
__device__ __forceinline__ float bfv(unsigned short s){
  return __uint_as_float(((unsigned)s) << 16);
}

// Gather one 32-row M-tile of split-bf16 A-fragments from global fp32.
// A-row m: gate g=m&3, unit u = 8*mt + 4*((m>>2)&1) + (m>>3) -> lane's C regs
// q=4r+g cover consecutive units u0t+4*up .. +3.
// k map: k<DIN: Wih; k==BIASK: bih+bhh; H0<=k<H0+DL: Whh[k-H0]; else 0.
template<int KT>
__device__ void gatherA(short8v (&ah)[5], short8v (&al)[5], int lane, int mt,
                        const float* Wih, const float* Whh,
                        const float* bih, const float* bhh,
                        int DL, int DIN, int BIASK, int H0) {
  const int upg = lane >> 5, rl = lane & 31;
  const int g = rl & 3;
  const int u = 8*mt + 4*((rl >> 2) & 1) + (rl >> 3);
#pragma unroll
  for (int kt = 0; kt < KT; ++kt) {
#pragma unroll
    for (int j = 0; j < 8; ++j) {
      const int k = kt*16 + upg*8 + j;
      float v = 0.0f;
      if (u < DL) {
        const int srow = g*DL + u;
        if (k < DIN)                      v = Wih[srow*DIN + k];
        else if (k == BIASK)              v = bih[srow] + bhh[srow];
        else if (k >= H0 && k < H0 + DL)  v = Whh[srow*DL + (k - H0)];
      }
      const unsigned short hi = bfr(v);
      const unsigned short lo = bfr(v - bfv(hi));
      ah[kt][j] = (short)hi;
      al[kt][j] = (short)lo;
    }
  }
}

// One tile: B-frag reads via precomputed slot pointers (lo plane = +3840),
// 3-term MFMA chain, lane-local cell update, b64 hi/lo h write at wr.
template<int KT>
__device__ __forceinline__ void doTile(
    const short8v (&ah)[5], const short8v (&al)[5],
    const unsigned short* const (&bp)[KT],
    float (&cst)[4], unsigned short* wr, float* scrp) {
  short8v Bh[KT], Bl[KT];
#pragma unroll
  for (int kt = 0; kt < KT; ++kt) {
    Bh[kt] = *(const short8v*)(bp[kt]);
    Bl[kt] = *(const short8v*)(bp[kt] + 3840);
  }
  f32x16 acc = {};
#pragma unroll
  for (int kt = 0; kt < KT; ++kt)
    acc = __builtin_amdgcn_mfma_f32_32x32x16_bf16(ah[kt], Bh[kt], acc, 0, 0, 0);
#pragma unroll
  for (int kt = 0; kt < KT; ++kt)
    acc = __builtin_amdgcn_mfma_f32_32x32x16_bf16(ah[kt], Bl[kt], acc, 0, 0, 0);
#pragma unroll
  for (int kt = 0; kt < KT; ++kt)
    acc = __builtin_amdgcn_mfma_f32_32x32x16_bf16(al[kt], Bh[kt], acc, 0, 0, 0);
  float h[4];
#pragma unroll
  for (int r = 0; r < 4; ++r) {
    const float ii = sigm(acc[4*r+0]);
    const float ff = sigm(acc[4*r+1]);
    const float g2 = tanhp(acc[4*r+2]);
    const float oo = sigm(acc[4*r+3]);
    cst[r] = fmaf(ff, cst[r], ii * g2);
    h[r] = oo * tanhp(cst[r]);
  }
  const unsigned pa = cvtpk(h[0], h[1]);
  const unsigned pb = cvtpk(h[2], h[3]);
  const float f0 = h[0] - __uint_as_float(pa << 16);
  const float f1 = h[1] - __uint_as_float(pa & 0xFFFF0000u);
  const float f2 = h[2] - __uint_as_float(pb << 16);
  const float f3 = h[3] - __uint_as_float(pb & 0xFFFF0000u);
  uint2 vh; vh.x = pa;            vh.y = pb;
  uint2 vl; vl.x = cvtpk(f0, f1); vl.y = cvtpk(f2, f3);
  *(uint2*)wr = vh;
  *(uint2*)(wr + 3840) = vl;
  if (scrp) *(float4*)scrp = make_float4(h[0], h[1], h[2], h[3]);
}

// x staging into SX slot: elem el, half -> k = half*4+j (half1: x4,x5,x6,1.0)
__device__ __forceinline__ void writeX(unsigned short* plane, int el, int half,
                                       float v0, float v1, float v2, float v3) {
  const unsigned pa = cvtpk(v0, v1), pb = cvtpk(v2, v3);
  const float f0 = v0 - __uint_as_float(pa << 16);
  const float f1 = v1 - __uint_as_float(pa & 0xFFFF0000u);
  const float f2 = v2 - __uint_as_float(pb << 16);
  const float f3 = v3 - __uint_as_float(pb & 0xFFFF0000u);
  uint2 vh; vh.x = pa;            vh.y = pb;
  uint2 vl; vl.x = cvtpk(f0, f1); vl.y = cvtpk(f2, f3);
  const int a = (el << 3) + (half << 2);
  *(uint2*)(plane + a) = vh;
  *(uint2*)(plane + a + 3840) = vl;
}

__global__ void __launch_bounds__(NT, 4)
lstm_pipe16(const float* __restrict__ x,
            const float* __restrict__ Wih1, const float* __restrict__ Whh1,
            const float* __restrict__ bih1, const float* __restrict__ bhh1,
            const float* __restrict__ Wih2, const float* __restrict__ Whh2,
            const float* __restrict__ bih2, const float* __restrict__ bhh2,
            const float* __restrict__ Wih3, const float* __restrict__ Whh3,
            const float* __restrict__ bih3, const float* __restrict__ bhh3,
            const float* __restrict__ Wih4, const float* __restrict__ Whh4,
            const float* __restrict__ bih4, const float* __restrict__ bhh4,
            const float* __restrict__ Wl, const float* __restrict__ bl,
            float* __restrict__ out) {
  __shared__ __align__(16) unsigned short S[STOTU];
  __shared__ __align__(16) float scrA[2*32*44];
  __shared__ __align__(16) float obuf[32*68];
  __shared__ float wlS[41];

  const int tid  = threadIdx.x;
  const int wv   = tid >> 6, lane = tid & 63;
  const int n    = lane & 31, up = lane >> 5;
  const int n8   = n << 3;
  const long gb  = (long)blockIdx.x * 32;

  for (int i = tid; i < STOTU/2; i += NT) ((unsigned*)S)[i] = 0u;
  if (tid < 41) wlS[tid] = (tid < 40) ? Wl[tid] : bl[0];
  __syncthreads();
  if (tid < 256) S[ONEO + tid] = 0x3F80;   // shared ones slot (hi only)
  // x(0) -> parity 0 SX (wv15)
  if (wv == 15) {
    const int el = lane >> 1, half = lane & 1;
    const float* xa = x + (gb + el)*(TS*7) + (half << 2);
    writeX(S + 0, el, half, xa[0], xa[1], xa[2], half ? 1.0f : xa[3]);
  }

  // ---- one-time A-frag gather; role table (SIMD-balanced by wv&3) ----
  // wv: 0=L1m0 1=L1m1 2=L2m2 3=L3m3 4=L2m0 5=L2m1 6=L3m2 7=L4m3
  //     8=L4m0 9=L4m1 10=L4m2 11=L4m4 12=L3m0 13=L3m1 14=y 15=x
  short8v ah[5], al[5];
  if      (wv == 0)  gatherA<2>(ah,al,lane,0,Wih1,Whh1,bih1,bhh1,15,7,7,8);
  else if (wv == 1)  gatherA<2>(ah,al,lane,1,Wih1,Whh1,bih1,bhh1,15,7,7,8);
  else if (wv == 4)  gatherA<3>(ah,al,lane,0,Wih2,Whh2,bih2,bhh2,20,15,16,24);
  else if (wv == 5)  gatherA<3>(ah,al,lane,1,Wih2,Whh2,bih2,bhh2,20,15,16,24);
  else if (wv == 2)  gatherA<3>(ah,al,lane,2,Wih2,Whh2,bih2,bhh2,20,15,16,24);
  else if (wv == 12) gatherA<4>(ah,al,lane,0,Wih3,Whh3,bih3,bhh3,30,20,24,32);
  else if (wv == 13) gatherA<4>(ah,al,lane,1,Wih3,Whh3,bih3,bhh3,30,20,24,32);
  else if (wv == 6)  gatherA<4>(ah,al,lane,2,Wih3,Whh3,bih3,bhh3,30,20,24,32);
  else if (wv == 3)  gatherA<4>(ah,al,lane,3,Wih3,Whh3,bih3,bhh3,30,20,24,32);
  else if (wv == 8)  gatherA<5>(ah,al,lane,0,Wih4,Whh4,bih4,bhh4,40,30,32,40);
  else if (wv == 9)  gatherA<5>(ah,al,lane,1,Wih4,Whh4,bih4,bhh4,40,30,32,40);
  else if (wv == 10) gatherA<5>(ah,al,lane,2,Wih4,Whh4,bih4,bhh4,40,30,32,40);
  else if (wv == 7)  gatherA<5>(ah,al,lane,3,Wih4,Whh4,bih4,bhh4,40,30,32,40);
  else if (wv == 11) gatherA<5>(ah,al,lane,4,Wih4,Whh4,bih4,bhh4,40,30,32,40);

  float cst[4] = {0,0,0,0};
  __syncthreads();

#pragma unroll 1
  for (int P = 0; P < TS + 4; ++P) {
    const int cur = P & 1, wp = cur ^ 1;
    const unsigned short* hp = S + cur*7680;
    unsigned short* wpp = S + wp*7680;
    float* scrW = scrA + wp*(32*44);

    if (wv <= 1) {                    // L1 m0/m1
      if (P <= TS-1) {
        const int mt = wv;
        const unsigned short* bp[2];
        bp[0] = hp + (up ? RH1 : 0) + n8;
        bp[1] = up ? (S + ZO + n8) : (hp + RH1 + 256 + n8);
        unsigned short* wr = wpp + RH1 + mt*256 + n8 + 4*up;
        doTile<2>(ah, al, bp, cst, wr, nullptr);
      }
    } else if (wv == 4 || wv == 5 || wv == 2) {   // L2 m0/m1/m2
      if (P >= 1 && P <= TS) {
        const int mt = (wv == 2) ? 2 : (wv - 4);
        const unsigned short* bp[3];
        bp[0] = hp + RH1 + (up ? 256 : 0) + n8;
        bp[1] = up ? (hp + RH2 + n8) : (S + ONEO + n8);
        bp[2] = hp + RH2 + (up ? 512 : 256) + n8;
        unsigned short* wr = wpp + RH2 + mt*256 + n8 + 4*up;
        doTile<3>(ah, al, bp, cst, wr, nullptr);
      }
    } else if (wv == 12 || wv == 13 || wv == 6 || wv == 3) {   // L3 m0..m3
      if (P >= 2 && P <= TS+1) {
        const int mt = (wv == 12) ? 0 : (wv == 13) ? 1 : (wv == 6) ? 2 : 3;
        const unsigned short* bp[4];
        bp[0] = hp + RH2 + (up ? 256 : 0) + n8;
        bp[1] = up ? (S + ONEO + n8) : (hp + RH2 + 512 + n8);
        bp[2] = hp + RH3 + (up ? 256 : 0) + n8;
        bp[3] = hp + RH3 + (up ? 768 : 512) + n8;
        unsigned short* wr = wpp + RH3 + mt*256 + n8 + 4*up;
        doTile<4>(ah, al, bp, cst, wr, nullptr);
      }
    } else if (wv >= 7 && wv <= 11) {   // L4 m0..m4
      if (P >= 3 && P <= TS+2) {
        const int mt = (wv == 7) ? 3 : (wv == 11) ? 4 : (wv - 8);
        const unsigned short* bp[5];
        bp[0] = hp + RH3 + (up ? 256 : 0) + n8;
        bp[1] = hp + RH3 + (up ? 768 : 512) + n8;
        bp[2] = up ? (hp + RH4 + n8) : (S + ONEO + n8);
        bp[3] = hp + RH4 + (up ? 512 : 256) + n8;
        bp[4] = hp + RH4 + (up ? 1024 : 768) + n8;
        unsigned short* wr = wpp + RH4 + mt*256 + n8 + 4*up;
        float* sc = scrW + n*44 + mt*8 + 4*up;
        doTile<5>(ah, al, bp, cst, wr, sc);
      }
    } else if (wv == 14) {   // y(P-4) + flush
      if (P >= 4) {
        const int ty = P - 4;
        const float* sp = scrA + cur*(32*44) + n*44 + up*20;
        float part = 0.0f;
#pragma unroll
        for (int q = 0; q < 5; ++q) {
          const float4 v = *(const float4*)(sp + 4*q);
          const float4 w = *(const float4*)(wlS + up*20 + 4*q);
          part = fmaf(v.x, w.x, fmaf(v.y, w.y, fmaf(v.z, w.z, fmaf(v.w, w.w, part))));
        }
        part += __shfl_xor(part, 32);
        if (lane < 32) obuf[n*68 + (ty & 63)] = part + wlS[40];
        if ((ty & 63) == 63) {
#pragma unroll
          for (int it = 0; it < 8; ++it) {
            const int row = it*4 + (lane >> 4), col = (lane & 15) << 2;
            const float4 v = *(const float4*)(obuf + row*68 + col);
            *(float4*)(out + (gb + row)*TS + (ty - 63) + col) = v;
          }
        }
      }
    } else {   // wv == 15: x(P+1) -> write parity SX
      if (P <= TS-2) {
        const int el = lane >> 1, half = lane & 1;
        const float* xa = x + (gb + el)*(TS*7) + (P + 1)*7 + (half << 2);
        const float v0 = xa[0], v1 = xa[1], v2 = xa[2];
        const float v3 = half ? 1.0f : xa[3];
        writeX(wpp, el, half, v0, v1, v2, v3);
      }
    }
    __syncthreads();
  }
}

extern "C" void kernel_launch(void* const* d_in, const int* in_sizes, int n_in,
                              void* d_out, int out_size, void* d_ws, size_t ws_size,
                              hipStream_t stream) {
  lstm_pipe16<<<dim3(8192/32), dim3(NT), 0, stream>>>(
      (const float*)d_in[0],
      (const float*)d_in[1],  (const float*)d_in[2],  (const float*)d_in[3],  (const float*)d_in[4],
      (const float*)d_in[5],  (const float*)d_in[6],  (const float*)d_in[7],  (const float*)d_in[8],
      (const float*)d_in[9],  (const float*)d_in[10], (const float*)d_in[11], (const float*)d_in[12],
      (const float*)d_in[13], (const float*)d_in[14], (const float*)d_in[15], (const float*)d_in[16],
      (const float*)d_in[17], (const float*)d_in[18],
      (float*)d_out);
}